// Round 1
// baseline (6826.745 us; speedup 1.0000x reference)
//
#include <hip/hip_runtime.h>
#include <math.h>

// Problem constants (B,S,D,H fixed by the reference)
#define BB 4
#define SS 1024
#define DD 768
#define HH 12
#define DHD 64
#define MROWS (BB * SS)        // 4096
#define FF (4 * DD)            // 3072

// ---------------------------------------------------------------------------
// GEMM: C[M,N] = A[M,K] @ B[K,N]  (+bias) (gelu) (+resid)
// Tiles: 64x64 per block (256 threads, 4x4 per thread), K-step 16.
// b_headmajor: B is [H, K, 64] per-head layout (Wq/Wk/Wv), valid because
// BN == 64 == Dh so one N-tile == one head.
// M % 64 == 0, N % 64 == 0, K % 16 == 0 required (always true here).
// ---------------------------------------------------------------------------
__global__ __launch_bounds__(256) void gemm_kernel(
    const float* __restrict__ A, const float* __restrict__ Bm,
    float* __restrict__ C, int M, int N, int K,
    const float* __restrict__ bias, const float* __restrict__ resid,
    int do_gelu, int b_headmajor)
{
    __shared__ float As[16][64];
    __shared__ float Bs[16][64];

    const int tid = threadIdx.x;
    const int tx = tid & 15;        // N direction (4 cols each)
    const int ty = tid >> 4;        // M direction (4 rows each)
    const int row0 = blockIdx.y * 64;
    const int col0 = blockIdx.x * 64;

    const int a_m = tid >> 2;           // 0..63
    const int a_k = (tid & 3) * 4;      // 0,4,8,12
    const int b_k = tid >> 4;           // 0..15
    const int b_n = (tid & 15) * 4;     // 0..60

    // Per-head base for head-major B (one tile == one head)
    const float* Bhead = b_headmajor ? (Bm + (size_t)(col0 >> 6) * K * 64) : nullptr;

    float acc[4][4];
#pragma unroll
    for (int i = 0; i < 4; ++i)
#pragma unroll
        for (int j = 0; j < 4; ++j) acc[i][j] = 0.0f;

    for (int k0 = 0; k0 < K; k0 += 16) {
        // Load A tile (64x16), store transposed As[k][m]
        float4 av = *(const float4*)(A + (size_t)(row0 + a_m) * K + k0 + a_k);
        As[a_k + 0][a_m] = av.x;
        As[a_k + 1][a_m] = av.y;
        As[a_k + 2][a_m] = av.z;
        As[a_k + 3][a_m] = av.w;
        // Load B tile (16x64)
        float4 bv;
        if (b_headmajor) {
            bv = *(const float4*)(Bhead + (size_t)(k0 + b_k) * 64 + b_n);
        } else {
            bv = *(const float4*)(Bm + (size_t)(k0 + b_k) * N + col0 + b_n);
        }
        *(float4*)(&Bs[b_k][b_n]) = bv;
        __syncthreads();

#pragma unroll
        for (int k = 0; k < 16; ++k) {
            float4 a4 = *(const float4*)(&As[k][ty * 4]);
            float4 b4 = *(const float4*)(&Bs[k][tx * 4]);
            float ar[4] = {a4.x, a4.y, a4.z, a4.w};
            float br[4] = {b4.x, b4.y, b4.z, b4.w};
#pragma unroll
            for (int i = 0; i < 4; ++i)
#pragma unroll
                for (int j = 0; j < 4; ++j) acc[i][j] += ar[i] * br[j];
        }
        __syncthreads();
    }

    // Epilogue: bias -> gelu -> residual -> store
#pragma unroll
    for (int i = 0; i < 4; ++i) {
        const int row = row0 + ty * 4 + i;
        const int col = col0 + tx * 4;
        float c[4] = {acc[i][0], acc[i][1], acc[i][2], acc[i][3]};
        if (bias) {
#pragma unroll
            for (int j = 0; j < 4; ++j) c[j] += bias[col + j];
        }
        if (do_gelu) {
#pragma unroll
            for (int j = 0; j < 4; ++j) {
                float v = c[j];
                c[j] = 0.5f * v * (1.0f + erff(v * 0.70710678118654752f));
            }
        }
        if (resid) {
            const float4 r = *(const float4*)(resid + (size_t)row * N + col);
            c[0] += r.x; c[1] += r.y; c[2] += r.z; c[3] += r.w;
        }
        float4 o = make_float4(c[0], c[1], c[2], c[3]);
        *(float4*)(C + (size_t)row * N + col) = o;
    }
}

// ---------------------------------------------------------------------------
// Attention: one block (256 threads) per (query s, b*h). Q,K,V are [B,S,H*Dh].
// Scores in LDS (S=1024 floats), softmax w/ max-sub, then PV.
// kmask: int mask over keys [B,S]; causal!=0 additionally limits t <= s.
// ---------------------------------------------------------------------------
__global__ __launch_bounds__(256) void attn_kernel(
    const float* __restrict__ Q, const float* __restrict__ K,
    const float* __restrict__ V, const int* __restrict__ kmask,
    float* __restrict__ O, int causal)
{
    const int s = blockIdx.x;
    const int bh = blockIdx.y;
    const int b = bh / HH;
    const int h = bh % HH;
    const int tid = threadIdx.x;

    __shared__ float q[DHD];
    __shared__ float p[SS];
    __shared__ float red[256];

    const size_t qoff = ((size_t)(b * SS + s)) * DD + h * DHD;
    if (tid < DHD) q[tid] = Q[qoff + tid] * 0.125f;  // 1/sqrt(64)
    __syncthreads();

    const int tlim = causal ? (s + 1) : SS;

    float lmax = -INFINITY;
    for (int t = tid; t < SS; t += 256) {
        float sc = -INFINITY;
        if (t < tlim && kmask[b * SS + t] != 0) {
            const float4* K4 = (const float4*)(K + ((size_t)(b * SS + t)) * DD + h * DHD);
            float dot = 0.0f;
#pragma unroll
            for (int d4 = 0; d4 < 16; ++d4) {
                float4 kv = K4[d4];
                dot += q[d4 * 4 + 0] * kv.x + q[d4 * 4 + 1] * kv.y +
                       q[d4 * 4 + 2] * kv.z + q[d4 * 4 + 3] * kv.w;
            }
            sc = dot;
        }
        p[t] = sc;
        lmax = fmaxf(lmax, sc);
    }
    red[tid] = lmax;
    __syncthreads();
    for (int off = 128; off > 0; off >>= 1) {
        if (tid < off) red[tid] = fmaxf(red[tid], red[tid + off]);
        __syncthreads();
    }
    const float mx = red[0];
    __syncthreads();

    float lsum = 0.0f;
    for (int t = tid; t < SS; t += 256) {
        float e = expf(p[t] - mx);   // exp(-inf - mx) == 0 for masked
        p[t] = e;
        lsum += e;
    }
    red[tid] = lsum;
    __syncthreads();
    for (int off = 128; off > 0; off >>= 1) {
        if (tid < off) red[tid] += red[tid + off];
        __syncthreads();
    }
    const float denom = red[0];
    __syncthreads();

    // PV: 64 dims x 4 t-groups
    const int d = tid & 63;
    const int g = tid >> 6;
    float acc = 0.0f;
    for (int t = g; t < SS; t += 4) {
        acc += p[t] * V[((size_t)(b * SS + t)) * DD + h * DHD + d];
    }
    red[tid] = acc;
    __syncthreads();
    if (tid < DHD) {
        float tot = red[tid] + red[64 + tid] + red[128 + tid] + red[192 + tid];
        O[((size_t)(b * SS + s)) * DD + h * DHD + tid] = tot / denom;
    }
}

// ---------------------------------------------------------------------------
// LayerNorm over last dim (768). One block (256 threads) per row.
// ---------------------------------------------------------------------------
__global__ __launch_bounds__(256) void ln_kernel(
    const float* __restrict__ X, const float* __restrict__ gma,
    const float* __restrict__ bta, float* __restrict__ Y)
{
    const int row = blockIdx.x;
    const int tid = threadIdx.x;
    const float* x = X + (size_t)row * DD;

    const float v0 = x[tid], v1 = x[tid + 256], v2 = x[tid + 512];

    __shared__ float sd[256];
    sd[tid] = v0 + v1 + v2;
    __syncthreads();
    for (int off = 128; off > 0; off >>= 1) {
        if (tid < off) sd[tid] += sd[tid + off];
        __syncthreads();
    }
    const float mean = sd[0] * (1.0f / 768.0f);
    __syncthreads();

    const float q0 = v0 - mean, q1 = v1 - mean, q2 = v2 - mean;
    sd[tid] = q0 * q0 + q1 * q1 + q2 * q2;
    __syncthreads();
    for (int off = 128; off > 0; off >>= 1) {
        if (tid < off) sd[tid] += sd[tid + off];
        __syncthreads();
    }
    const float var = sd[0] * (1.0f / 768.0f);
    const float inv = rsqrtf(var + 1e-5f);

    float* y = Y + (size_t)row * DD;
    y[tid]       = q0 * inv * gma[tid]       + bta[tid];
    y[tid + 256] = q1 * inv * gma[tid + 256] + bta[tid + 256];
    y[tid + 512] = q2 * inv * gma[tid + 512] + bta[tid + 512];
}

// ---------------------------------------------------------------------------
extern "C" void kernel_launch(void* const* d_in, const int* in_sizes, int n_in,
                              void* d_out, int out_size, void* d_ws, size_t ws_size,
                              hipStream_t stream)
{
    (void)in_sizes; (void)n_in; (void)out_size; (void)ws_size;

    const float* key_enc   = (const float*)d_in[0];
    const float* value_enc = (const float*)d_in[1];
    const float* x         = (const float*)d_in[2];
    const int*   src_mask  = (const int*)d_in[3];
    const int*   tgt_mask  = (const int*)d_in[4];
    const float* Wq_m = (const float*)d_in[5];
    const float* Wk_m = (const float*)d_in[6];
    const float* Wv_m = (const float*)d_in[7];
    const float* Wo_m = (const float*)d_in[8];
    const float* Wq_c = (const float*)d_in[9];
    const float* Wk_c = (const float*)d_in[10];
    const float* Wv_c = (const float*)d_in[11];
    const float* Wo_c = (const float*)d_in[12];
    const float* ln1_g = (const float*)d_in[13];
    const float* ln1_b = (const float*)d_in[14];
    const float* ln2_g = (const float*)d_in[15];
    const float* ln2_b = (const float*)d_in[16];
    const float* ln3_g = (const float*)d_in[17];
    const float* ln3_b = (const float*)d_in[18];
    const float* W1 = (const float*)d_in[19];
    const float* b1 = (const float*)d_in[20];
    const float* W2 = (const float*)d_in[21];
    const float* b2 = (const float*)d_in[22];

    float* out = (float*)d_out;

    // Workspace layout (floats). 7 x 4096*768 = 88 MB.
    const size_t ACT = (size_t)MROWS * DD;  // 3145728
    float* ws  = (float*)d_ws;
    float* Qb  = ws;
    float* Kb  = Qb + ACT;
    float* Vb  = Kb + ACT;
    float* T1  = Vb + ACT;
    float* T2  = T1 + ACT;
    float* H1  = T2 + ACT;
    float* H2  = H1 + ACT;
    float* MID = Qb;  // [4096,3072] reuses Q/K/V/T1 region (4*ACT floats)

    const dim3 blk(256);
    const dim3 gProj(DD / 64, MROWS / 64);    // 12 x 64
    const dim3 gMlp1(FF / 64, MROWS / 64);    // 48 x 64
    const dim3 gAttn(SS, BB * HH);            // 1024 x 48

    // ---- Self-attention ----
    gemm_kernel<<<gProj, blk, 0, stream>>>(x, Wq_m, Qb, MROWS, DD, DD, nullptr, nullptr, 0, 1);
    gemm_kernel<<<gProj, blk, 0, stream>>>(x, Wk_m, Kb, MROWS, DD, DD, nullptr, nullptr, 0, 1);
    gemm_kernel<<<gProj, blk, 0, stream>>>(x, Wv_m, Vb, MROWS, DD, DD, nullptr, nullptr, 0, 1);
    attn_kernel<<<gAttn, blk, 0, stream>>>(Qb, Kb, Vb, tgt_mask, T1, 1);
    gemm_kernel<<<gProj, blk, 0, stream>>>(T1, Wo_m, T2, MROWS, DD, DD, nullptr, x, 0, 0);
    ln_kernel<<<MROWS, blk, 0, stream>>>(T2, ln1_g, ln1_b, H1);

    // ---- Cross-attention ----
    gemm_kernel<<<gProj, blk, 0, stream>>>(H1, Wq_c, Qb, MROWS, DD, DD, nullptr, nullptr, 0, 1);
    gemm_kernel<<<gProj, blk, 0, stream>>>(key_enc, Wk_c, Kb, MROWS, DD, DD, nullptr, nullptr, 0, 1);
    gemm_kernel<<<gProj, blk, 0, stream>>>(value_enc, Wv_c, Vb, MROWS, DD, DD, nullptr, nullptr, 0, 1);
    attn_kernel<<<gAttn, blk, 0, stream>>>(Qb, Kb, Vb, src_mask, T1, 0);
    gemm_kernel<<<gProj, blk, 0, stream>>>(T1, Wo_c, T2, MROWS, DD, DD, nullptr, H1, 0, 0);
    ln_kernel<<<MROWS, blk, 0, stream>>>(T2, ln2_g, ln2_b, H2);

    // ---- MLP ----
    gemm_kernel<<<gMlp1, blk, 0, stream>>>(H2, W1, MID, MROWS, FF, DD, b1, nullptr, 1, 0);
    gemm_kernel<<<gProj, blk, 0, stream>>>(MID, W2, T2, MROWS, DD, FF, b2, H2, 0, 0);
    ln_kernel<<<MROWS, blk, 0, stream>>>(T2, ln3_g, ln3_b, out);
}

// Round 2
// 1661.117 us; speedup vs baseline: 4.1097x; 4.1097x over previous
//
#include <hip/hip_runtime.h>
#include <math.h>

// Problem constants (B,S,D,H fixed by the reference)
#define BB 4
#define SS 1024
#define DD 768
#define HH 12
#define DHD 64
#define MROWS (BB * SS)        // 4096
#define FF (4 * DD)            // 3072
#define PAD 68                 // LDS row stride (floats): 16B-aligned, conflict-free

// ---------------------------------------------------------------------------
// GEMM: C[M,N] = A[M,K] @ B[K,N]  (+bias) (gelu) (+resid)
// Tiles: 64x64 per block (256 threads, 4x4 per thread), K-step 16.
// b_headmajor: B is [H, K, 64] per-head layout (Wq/Wk/Wv); BN==64==Dh so one
// N-tile == one head.
// ---------------------------------------------------------------------------
__global__ __launch_bounds__(256) void gemm_kernel(
    const float* __restrict__ A, const float* __restrict__ Bm,
    float* __restrict__ C, int M, int N, int K,
    const float* __restrict__ bias, const float* __restrict__ resid,
    int do_gelu, int b_headmajor)
{
    __shared__ float As[16][64];
    __shared__ float Bs[16][64];

    const int tid = threadIdx.x;
    const int tx = tid & 15;
    const int ty = tid >> 4;
    const int row0 = blockIdx.y * 64;
    const int col0 = blockIdx.x * 64;

    const int a_m = tid >> 2;
    const int a_k = (tid & 3) * 4;
    const int b_k = tid >> 4;
    const int b_n = (tid & 15) * 4;

    const float* Bhead = b_headmajor ? (Bm + (size_t)(col0 >> 6) * K * 64) : nullptr;

    float acc[4][4];
#pragma unroll
    for (int i = 0; i < 4; ++i)
#pragma unroll
        for (int j = 0; j < 4; ++j) acc[i][j] = 0.0f;

    for (int k0 = 0; k0 < K; k0 += 16) {
        float4 av = *(const float4*)(A + (size_t)(row0 + a_m) * K + k0 + a_k);
        As[a_k + 0][a_m] = av.x;
        As[a_k + 1][a_m] = av.y;
        As[a_k + 2][a_m] = av.z;
        As[a_k + 3][a_m] = av.w;
        float4 bv;
        if (b_headmajor) {
            bv = *(const float4*)(Bhead + (size_t)(k0 + b_k) * 64 + b_n);
        } else {
            bv = *(const float4*)(Bm + (size_t)(k0 + b_k) * N + col0 + b_n);
        }
        *(float4*)(&Bs[b_k][b_n]) = bv;
        __syncthreads();

#pragma unroll
        for (int k = 0; k < 16; ++k) {
            float4 a4 = *(const float4*)(&As[k][ty * 4]);
            float4 b4 = *(const float4*)(&Bs[k][tx * 4]);
            float ar[4] = {a4.x, a4.y, a4.z, a4.w};
            float br[4] = {b4.x, b4.y, b4.z, b4.w};
#pragma unroll
            for (int i = 0; i < 4; ++i)
#pragma unroll
                for (int j = 0; j < 4; ++j) acc[i][j] += ar[i] * br[j];
        }
        __syncthreads();
    }

#pragma unroll
    for (int i = 0; i < 4; ++i) {
        const int row = row0 + ty * 4 + i;
        const int col = col0 + tx * 4;
        float c[4] = {acc[i][0], acc[i][1], acc[i][2], acc[i][3]};
        if (bias) {
#pragma unroll
            for (int j = 0; j < 4; ++j) c[j] += bias[col + j];
        }
        if (do_gelu) {
#pragma unroll
            for (int j = 0; j < 4; ++j) {
                float v = c[j];
                c[j] = 0.5f * v * (1.0f + erff(v * 0.70710678118654752f));
            }
        }
        if (resid) {
            const float4 r = *(const float4*)(resid + (size_t)row * N + col);
            c[0] += r.x; c[1] += r.y; c[2] += r.z; c[3] += r.w;
        }
        float4 o = make_float4(c[0], c[1], c[2], c[3]);
        *(float4*)(C + (size_t)row * N + col) = o;
    }
}

// ---------------------------------------------------------------------------
// Tiled flash attention: one block per (query-tile of 64, b*h).
// 256 threads = 16x16, each computing a 4x4 fragment of the 64x64 score tile
// and a 4x4 fragment of the 64-dim output. Online softmax (running m,l per
// query row, reduced across the 16 tx-lanes via shfl_xor).
// LDS: Qt/Kt transposed [d][row] (staged via 4x4 register-block transpose ->
// float4 column writes, conflict-free), V row-major, P transposed [key][row].
// ---------------------------------------------------------------------------
__global__ __launch_bounds__(256) void attn_tiled_kernel(
    const float* __restrict__ Q, const float* __restrict__ K,
    const float* __restrict__ V, const int* __restrict__ kmask,
    float* __restrict__ O, int causal)
{
    const int qt = blockIdx.x;           // query tile index (0..15)
    const int bh = blockIdx.y;           // b*H + h
    const int b  = bh / HH;
    const int h  = bh % HH;
    const int tid = threadIdx.x;
    const int tx = tid & 15;
    const int ty = tid >> 4;

    __shared__ float Qt[64][PAD];        // Qt[d][qrow]  (pre-scaled)
    __shared__ float Kt[64][PAD];        // Kt[d][krow]
    __shared__ float Vs[64][PAD];        // Vs[krow][d]
    __shared__ float Pt[64][PAD];        // Pt[krow][qrow]

    const int row0 = qt * 64;

    // ---- stage Q transposed (scaled by 1/sqrt(64)) ----
    {
        const int d4 = tid & 15;             // float4 index along d
        const int rg = (tid >> 4) * 4;       // row group of 4
        float4 rv[4];
#pragma unroll
        for (int k = 0; k < 4; ++k)
            rv[k] = *(const float4*)(Q + ((size_t)(b * SS + row0 + rg + k)) * DD + h * DHD + d4 * 4);
#pragma unroll
        for (int dd = 0; dd < 4; ++dd) {
            float4 w = make_float4((&rv[0].x)[dd] * 0.125f, (&rv[1].x)[dd] * 0.125f,
                                   (&rv[2].x)[dd] * 0.125f, (&rv[3].x)[dd] * 0.125f);
            *(float4*)(&Qt[d4 * 4 + dd][rg]) = w;
        }
    }

    float m[4], l[4], acc[4][4];
#pragma unroll
    for (int i = 0; i < 4; ++i) {
        m[i] = -INFINITY; l[i] = 0.0f;
#pragma unroll
        for (int k = 0; k < 4; ++k) acc[i][k] = 0.0f;
    }

    const int nkt = causal ? (qt + 1) : 16;

    for (int kt = 0; kt < nkt; ++kt) {
        const int kcol0 = kt * 64;

        // ---- stage K transposed + V row-major ----
        {
            const int d4 = tid & 15;
            const int rg = (tid >> 4) * 4;
            float4 rv[4];
#pragma unroll
            for (int k = 0; k < 4; ++k)
                rv[k] = *(const float4*)(K + ((size_t)(b * SS + kcol0 + rg + k)) * DD + h * DHD + d4 * 4);
#pragma unroll
            for (int dd = 0; dd < 4; ++dd) {
                float4 w = make_float4((&rv[0].x)[dd], (&rv[1].x)[dd],
                                       (&rv[2].x)[dd], (&rv[3].x)[dd]);
                *(float4*)(&Kt[d4 * 4 + dd][rg]) = w;
            }
#pragma unroll
            for (int it = 0; it < 4; ++it) {
                const int idx = it * 256 + tid;
                const int r = idx >> 4;
                const int f4 = idx & 15;
                *(float4*)(&Vs[r][f4 * 4]) =
                    *(const float4*)(V + ((size_t)(b * SS + kcol0 + r)) * DD + h * DHD + f4 * 4);
            }
        }
        __syncthreads();

        // ---- QK^T: s[4][4] over this tile ----
        float s[4][4];
#pragma unroll
        for (int i = 0; i < 4; ++i)
#pragma unroll
            for (int j = 0; j < 4; ++j) s[i][j] = 0.0f;

        for (int d = 0; d < 64; ++d) {
            float4 q4 = *(const float4*)(&Qt[d][ty * 4]);
            float4 k4 = *(const float4*)(&Kt[d][tx * 4]);
            float qr[4] = {q4.x, q4.y, q4.z, q4.w};
            float kr[4] = {k4.x, k4.y, k4.z, k4.w};
#pragma unroll
            for (int i = 0; i < 4; ++i)
#pragma unroll
                for (int j = 0; j < 4; ++j) s[i][j] += qr[i] * kr[j];
        }

        // ---- mask + online softmax ----
        int kc[4]; int ok[4];
        const bool diag = (causal != 0) && (kt == nkt - 1);
#pragma unroll
        for (int j = 0; j < 4; ++j) {
            kc[j] = kcol0 + tx * 4 + j;
            ok[j] = kmask[b * SS + kc[j]];
        }

#pragma unroll
        for (int i = 0; i < 4; ++i) {
            const int row = row0 + ty * 4 + i;
            float mx = -INFINITY;
#pragma unroll
            for (int j = 0; j < 4; ++j) {
                const bool allow = (ok[j] != 0) && (!diag || kc[j] <= row);
                s[i][j] = allow ? s[i][j] : -INFINITY;
                mx = fmaxf(mx, s[i][j]);
            }
            mx = fmaxf(mx, __shfl_xor(mx, 1));
            mx = fmaxf(mx, __shfl_xor(mx, 2));
            mx = fmaxf(mx, __shfl_xor(mx, 4));
            mx = fmaxf(mx, __shfl_xor(mx, 8));

            const float nm = fmaxf(m[i], mx);
            if (nm > -INFINITY) {
                const float sc = __expf(m[i] - nm);   // 0 if m[i] was -inf
                float rs = 0.0f;
#pragma unroll
                for (int j = 0; j < 4; ++j) {
                    const float p = __expf(s[i][j] - nm);  // -inf -> 0
                    s[i][j] = p;
                    rs += p;
                }
                rs += __shfl_xor(rs, 1);
                rs += __shfl_xor(rs, 2);
                rs += __shfl_xor(rs, 4);
                rs += __shfl_xor(rs, 8);
                l[i] = l[i] * sc + rs;
                m[i] = nm;
#pragma unroll
                for (int k = 0; k < 4; ++k) acc[i][k] *= sc;
            } else {
#pragma unroll
                for (int j = 0; j < 4; ++j) s[i][j] = 0.0f;
            }
        }

        // ---- write P transposed: Pt[key][qrow] ----
#pragma unroll
        for (int j = 0; j < 4; ++j) {
            *(float4*)(&Pt[tx * 4 + j][ty * 4]) =
                make_float4(s[0][j], s[1][j], s[2][j], s[3][j]);
        }
        __syncthreads();

        // ---- PV: acc[i][k] += P[i][jj] * V[jj][k] ----
        for (int jj = 0; jj < 64; ++jj) {
            float4 p4 = *(const float4*)(&Pt[jj][ty * 4]);
            float4 v4 = *(const float4*)(&Vs[jj][tx * 4]);
            float pr[4] = {p4.x, p4.y, p4.z, p4.w};
            float vr[4] = {v4.x, v4.y, v4.z, v4.w};
#pragma unroll
            for (int i = 0; i < 4; ++i)
#pragma unroll
                for (int k = 0; k < 4; ++k) acc[i][k] += pr[i] * vr[k];
        }
        __syncthreads();   // before next tile's staging overwrites Kt/Vs
    }

    // ---- epilogue: O = acc / l ----
#pragma unroll
    for (int i = 0; i < 4; ++i) {
        const float inv = 1.0f / l[i];
        float4 o = make_float4(acc[i][0] * inv, acc[i][1] * inv,
                               acc[i][2] * inv, acc[i][3] * inv);
        *(float4*)(O + ((size_t)(b * SS + row0 + ty * 4 + i)) * DD + h * DHD + tx * 4) = o;
    }
}

// ---------------------------------------------------------------------------
// LayerNorm over last dim (768). One block (256 threads) per row.
// ---------------------------------------------------------------------------
__global__ __launch_bounds__(256) void ln_kernel(
    const float* __restrict__ X, const float* __restrict__ gma,
    const float* __restrict__ bta, float* __restrict__ Y)
{
    const int row = blockIdx.x;
    const int tid = threadIdx.x;
    const float* x = X + (size_t)row * DD;

    const float v0 = x[tid], v1 = x[tid + 256], v2 = x[tid + 512];

    __shared__ float sd[256];
    sd[tid] = v0 + v1 + v2;
    __syncthreads();
    for (int off = 128; off > 0; off >>= 1) {
        if (tid < off) sd[tid] += sd[tid + off];
        __syncthreads();
    }
    const float mean = sd[0] * (1.0f / 768.0f);
    __syncthreads();

    const float q0 = v0 - mean, q1 = v1 - mean, q2 = v2 - mean;
    sd[tid] = q0 * q0 + q1 * q1 + q2 * q2;
    __syncthreads();
    for (int off = 128; off > 0; off >>= 1) {
        if (tid < off) sd[tid] += sd[tid + off];
        __syncthreads();
    }
    const float var = sd[0] * (1.0f / 768.0f);
    const float inv = rsqrtf(var + 1e-5f);

    float* y = Y + (size_t)row * DD;
    y[tid]       = q0 * inv * gma[tid]       + bta[tid];
    y[tid + 256] = q1 * inv * gma[tid + 256] + bta[tid + 256];
    y[tid + 512] = q2 * inv * gma[tid + 512] + bta[tid + 512];
}

// ---------------------------------------------------------------------------
extern "C" void kernel_launch(void* const* d_in, const int* in_sizes, int n_in,
                              void* d_out, int out_size, void* d_ws, size_t ws_size,
                              hipStream_t stream)
{
    (void)in_sizes; (void)n_in; (void)out_size; (void)ws_size;

    const float* key_enc   = (const float*)d_in[0];
    const float* value_enc = (const float*)d_in[1];
    const float* x         = (const float*)d_in[2];
    const int*   src_mask  = (const int*)d_in[3];
    const int*   tgt_mask  = (const int*)d_in[4];
    const float* Wq_m = (const float*)d_in[5];
    const float* Wk_m = (const float*)d_in[6];
    const float* Wv_m = (const float*)d_in[7];
    const float* Wo_m = (const float*)d_in[8];
    const float* Wq_c = (const float*)d_in[9];
    const float* Wk_c = (const float*)d_in[10];
    const float* Wv_c = (const float*)d_in[11];
    const float* Wo_c = (const float*)d_in[12];
    const float* ln1_g = (const float*)d_in[13];
    const float* ln1_b = (const float*)d_in[14];
    const float* ln2_g = (const float*)d_in[15];
    const float* ln2_b = (const float*)d_in[16];
    const float* ln3_g = (const float*)d_in[17];
    const float* ln3_b = (const float*)d_in[18];
    const float* W1 = (const float*)d_in[19];
    const float* b1 = (const float*)d_in[20];
    const float* W2 = (const float*)d_in[21];
    const float* b2 = (const float*)d_in[22];

    float* out = (float*)d_out;

    const size_t ACT = (size_t)MROWS * DD;
    float* ws  = (float*)d_ws;
    float* Qb  = ws;
    float* Kb  = Qb + ACT;
    float* Vb  = Kb + ACT;
    float* T1  = Vb + ACT;
    float* T2  = T1 + ACT;
    float* H1  = T2 + ACT;
    float* H2  = H1 + ACT;
    float* MID = Qb;  // [4096,3072] reuses Q/K/V/T1 region

    const dim3 blk(256);
    const dim3 gProj(DD / 64, MROWS / 64);
    const dim3 gMlp1(FF / 64, MROWS / 64);
    const dim3 gAttn(SS / 64, BB * HH);       // 16 x 48

    // ---- Self-attention ----
    gemm_kernel<<<gProj, blk, 0, stream>>>(x, Wq_m, Qb, MROWS, DD, DD, nullptr, nullptr, 0, 1);
    gemm_kernel<<<gProj, blk, 0, stream>>>(x, Wk_m, Kb, MROWS, DD, DD, nullptr, nullptr, 0, 1);
    gemm_kernel<<<gProj, blk, 0, stream>>>(x, Wv_m, Vb, MROWS, DD, DD, nullptr, nullptr, 0, 1);
    attn_tiled_kernel<<<gAttn, blk, 0, stream>>>(Qb, Kb, Vb, tgt_mask, T1, 1);
    gemm_kernel<<<gProj, blk, 0, stream>>>(T1, Wo_m, T2, MROWS, DD, DD, nullptr, x, 0, 0);
    ln_kernel<<<MROWS, blk, 0, stream>>>(T2, ln1_g, ln1_b, H1);

    // ---- Cross-attention ----
    gemm_kernel<<<gProj, blk, 0, stream>>>(H1, Wq_c, Qb, MROWS, DD, DD, nullptr, nullptr, 0, 1);
    gemm_kernel<<<gProj, blk, 0, stream>>>(key_enc, Wk_c, Kb, MROWS, DD, DD, nullptr, nullptr, 0, 1);
    gemm_kernel<<<gProj, blk, 0, stream>>>(value_enc, Wv_c, Vb, MROWS, DD, DD, nullptr, nullptr, 0, 1);
    attn_tiled_kernel<<<gAttn, blk, 0, stream>>>(Qb, Kb, Vb, src_mask, T1, 0);
    gemm_kernel<<<gProj, blk, 0, stream>>>(T1, Wo_c, T2, MROWS, DD, DD, nullptr, H1, 0, 0);
    ln_kernel<<<MROWS, blk, 0, stream>>>(T2, ln2_g, ln2_b, H2);

    // ---- MLP ----
    gemm_kernel<<<gMlp1, blk, 0, stream>>>(H2, W1, MID, MROWS, FF, DD, b1, nullptr, 1, 0);
    gemm_kernel<<<gProj, blk, 0, stream>>>(MID, W2, T2, MROWS, DD, FF, b2, H2, 0, 0);
    ln_kernel<<<MROWS, blk, 0, stream>>>(T2, ln3_g, ln3_b, out);
}

// Round 3
// 852.722 us; speedup vs baseline: 8.0058x; 1.9480x over previous
//
#include <hip/hip_runtime.h>
#include <math.h>

// Problem constants
#define BB 4
#define SS 1024
#define DD 768
#define HH 12
#define DHD 64
#define MROWS 4096
#define FF 3072
#define PAD 68                 // attn LDS row stride (floats)

typedef unsigned short u16;
typedef float f32x4 __attribute__((ext_vector_type(4)));
typedef __bf16 bf16x8 __attribute__((ext_vector_type(8)));
typedef unsigned short u16x8 __attribute__((ext_vector_type(8)));

static __device__ __forceinline__ float bf2f(u16 u) {
    union { unsigned int i; float f; } c; c.i = ((unsigned int)u) << 16; return c.f;
}
static __device__ __forceinline__ u16 f2bf(float f) {
    union { float f; unsigned int i; } c; c.f = f;
    unsigned int i = c.i + 0x7FFFu + ((c.i >> 16) & 1u);
    return (u16)(i >> 16);
}

// ---------------------------------------------------------------------------
// bf16 MFMA GEMM: C[M,N](fp32,+bias,+gelu,+resid) and/or Cbf[M,*ldcbf](bf16)
//   A  [M,K] bf16 row-major
//   Bt [N,K] bf16 row-major (i.e. B transposed)
// 128x128 tile, 256 threads = 4 waves (2x2), each wave 64x64 = 4x4 MFMA frags,
// BK=32. LDS row stride 40 bf16 (80B) -> conflict-free ds_read_b128.
// ---------------------------------------------------------------------------
#define LDST 40
__global__ __launch_bounds__(256) void gemm_bf16(
    const u16* __restrict__ A, const u16* __restrict__ Bt,
    int M, int N, int K,
    const float* __restrict__ bias, const float* __restrict__ resid,
    float* __restrict__ C, u16* __restrict__ Cbf, int ldcbf, int do_gelu)
{
    __shared__ u16 As[128 * LDST];
    __shared__ u16 Bs[128 * LDST];

    const int tid  = threadIdx.x;
    const int lane = tid & 63;
    const int wave = tid >> 6;
    const int row0 = blockIdx.y * 128;
    const int col0 = blockIdx.x * 128;
    const int wm = (wave >> 1) * 64;
    const int wn = (wave & 1) * 64;

    // staging: 2 x 16B chunks per thread for each of A,B
    const int srow = tid >> 1;            // 0..127
    const int skc  = (tid & 1) * 2;       // chunk pair: elems skc*8, skc*8+8

    const u16* Ap = A  + (size_t)(row0 + srow) * K + skc * 8;
    const u16* Bp = Bt + (size_t)(col0 + srow) * K + skc * 8;
    u16* AsW = &As[srow * LDST + skc * 8];
    u16* BsW = &Bs[srow * LDST + skc * 8];

    const int fr = lane & 15;
    const int fk = (lane >> 4) * 8;
    const u16* ArP = &As[(wm + fr) * LDST + fk];
    const u16* BrP = &Bs[(wn + fr) * LDST + fk];

    f32x4 acc[4][4] = {};

    for (int k0 = 0; k0 < K; k0 += 32) {
        u16x8 a0 = *(const u16x8*)(Ap + k0);
        u16x8 a1 = *(const u16x8*)(Ap + k0 + 8);
        u16x8 b0 = *(const u16x8*)(Bp + k0);
        u16x8 b1 = *(const u16x8*)(Bp + k0 + 8);
        if (k0) __syncthreads();          // prior tile's reads done
        *(u16x8*)(AsW)     = a0;
        *(u16x8*)(AsW + 8) = a1;
        *(u16x8*)(BsW)     = b0;
        *(u16x8*)(BsW + 8) = b1;
        __syncthreads();

        bf16x8 af[4], bfr[4];
#pragma unroll
        for (int mi = 0; mi < 4; ++mi)
            af[mi] = __builtin_bit_cast(bf16x8, *(const u16x8*)(ArP + mi * 16 * LDST));
#pragma unroll
        for (int ni = 0; ni < 4; ++ni)
            bfr[ni] = __builtin_bit_cast(bf16x8, *(const u16x8*)(BrP + ni * 16 * LDST));
#pragma unroll
        for (int mi = 0; mi < 4; ++mi)
#pragma unroll
            for (int ni = 0; ni < 4; ++ni)
                acc[mi][ni] = __builtin_amdgcn_mfma_f32_16x16x32_bf16(
                    af[mi], bfr[ni], acc[mi][ni], 0, 0, 0);
    }

    // Epilogue. C/D layout: col = lane&15, row = (lane>>4)*4 + reg  [m89]
    const int orow0 = row0 + wm + (lane >> 4) * 4;
    const int ocol0 = col0 + wn + (lane & 15);
#pragma unroll
    for (int mi = 0; mi < 4; ++mi) {
#pragma unroll
        for (int ni = 0; ni < 4; ++ni) {
            const int col = ocol0 + ni * 16;
            const float bv = bias ? bias[col] : 0.0f;
#pragma unroll
            for (int r = 0; r < 4; ++r) {
                const int row = orow0 + mi * 16 + r;
                float v = acc[mi][ni][r] + bv;
                if (do_gelu) v = 0.5f * v * (1.0f + erff(v * 0.70710678118654752f));
                if (resid) v += resid[(size_t)row * N + col];
                if (C)   C[(size_t)row * N + col] = v;
                if (Cbf) Cbf[(size_t)row * ldcbf + col] = f2bf(v);
            }
        }
    }
}

// ---------------------------------------------------------------------------
// Transpose + fp32->bf16: in [K,N] fp32 (batched) -> out [N,K] bf16
// ---------------------------------------------------------------------------
__global__ __launch_bounds__(256) void tcvt_kernel(
    const float* __restrict__ in, u16* __restrict__ out, int K, int N)
{
    __shared__ float t[32][33];
    const float* ib = in + (size_t)blockIdx.z * K * N;
    u16* ob = out + (size_t)blockIdx.z * K * N;
    const int n0 = blockIdx.x * 32, k0 = blockIdx.y * 32;
    const int tx = threadIdx.x & 31, ty = threadIdx.x >> 5;
#pragma unroll
    for (int j = 0; j < 4; ++j)
        t[ty + j * 8][tx] = ib[(size_t)(k0 + ty + j * 8) * N + n0 + tx];
    __syncthreads();
#pragma unroll
    for (int j = 0; j < 4; ++j)
        ob[(size_t)(n0 + ty + j * 8) * K + k0 + tx] = f2bf(t[tx][ty + j * 8]);
}

// fp32 -> bf16 elementwise (n multiple of 1024)
__global__ __launch_bounds__(256) void cvt_kernel(
    const float* __restrict__ in, u16* __restrict__ out, int n4)
{
    const int i = blockIdx.x * 256 + threadIdx.x;
    if (i < n4) {
        float4 v = ((const float4*)in)[i];
        ushort4 o;
        o.x = f2bf(v.x); o.y = f2bf(v.y); o.z = f2bf(v.z); o.w = f2bf(v.w);
        ((ushort4*)out)[i] = o;
    }
}

// ---------------------------------------------------------------------------
// Tiled flash attention (bf16 in/out, fp32 math). One block per (64-row query
// tile, b*h). Q/K/V row stride = ldq (elements). O row stride = DD.
// ---------------------------------------------------------------------------
__global__ __launch_bounds__(256) void attn_tiled_kernel(
    const u16* __restrict__ Q, const u16* __restrict__ K,
    const u16* __restrict__ V, int ldq, const int* __restrict__ kmask,
    u16* __restrict__ O, int causal)
{
    const int qt = blockIdx.x;
    const int bh = blockIdx.y;
    const int b  = bh / HH;
    const int h  = bh % HH;
    const int tid = threadIdx.x;
    const int tx = tid & 15;
    const int ty = tid >> 4;

    __shared__ float Qt[64][PAD];
    __shared__ float Kt[64][PAD];
    __shared__ float Vs[64][PAD];
    __shared__ float Pt[64][PAD];

    const int row0 = qt * 64;

    {   // stage Q transposed, scaled
        const int d4 = tid & 15;
        const int rg = (tid >> 4) * 4;
        float4 rv[4];
#pragma unroll
        for (int k = 0; k < 4; ++k) {
            ushort4 q4 = *(const ushort4*)(Q + (size_t)(b * SS + row0 + rg + k) * ldq + h * DHD + d4 * 4);
            rv[k] = make_float4(bf2f(q4.x), bf2f(q4.y), bf2f(q4.z), bf2f(q4.w));
        }
#pragma unroll
        for (int dd = 0; dd < 4; ++dd) {
            float4 w = make_float4((&rv[0].x)[dd] * 0.125f, (&rv[1].x)[dd] * 0.125f,
                                   (&rv[2].x)[dd] * 0.125f, (&rv[3].x)[dd] * 0.125f);
            *(float4*)(&Qt[d4 * 4 + dd][rg]) = w;
        }
    }

    float m[4], l[4], acc[4][4];
#pragma unroll
    for (int i = 0; i < 4; ++i) {
        m[i] = -INFINITY; l[i] = 0.0f;
#pragma unroll
        for (int k = 0; k < 4; ++k) acc[i][k] = 0.0f;
    }

    const int nkt = causal ? (qt + 1) : 16;

    for (int kt = 0; kt < nkt; ++kt) {
        const int kcol0 = kt * 64;
        {
            const int d4 = tid & 15;
            const int rg = (tid >> 4) * 4;
            float4 rv[4];
#pragma unroll
            for (int k = 0; k < 4; ++k) {
                ushort4 k4 = *(const ushort4*)(K + (size_t)(b * SS + kcol0 + rg + k) * ldq + h * DHD + d4 * 4);
                rv[k] = make_float4(bf2f(k4.x), bf2f(k4.y), bf2f(k4.z), bf2f(k4.w));
            }
#pragma unroll
            for (int dd = 0; dd < 4; ++dd) {
                float4 w = make_float4((&rv[0].x)[dd], (&rv[1].x)[dd],
                                       (&rv[2].x)[dd], (&rv[3].x)[dd]);
                *(float4*)(&Kt[d4 * 4 + dd][rg]) = w;
            }
#pragma unroll
            for (int it = 0; it < 4; ++it) {
                const int idx = it * 256 + tid;
                const int r = idx >> 4;
                const int f4 = idx & 15;
                ushort4 v4 = *(const ushort4*)(V + (size_t)(b * SS + kcol0 + r) * ldq + h * DHD + f4 * 4);
                *(float4*)(&Vs[r][f4 * 4]) =
                    make_float4(bf2f(v4.x), bf2f(v4.y), bf2f(v4.z), bf2f(v4.w));
            }
        }
        __syncthreads();

        float s[4][4];
#pragma unroll
        for (int i = 0; i < 4; ++i)
#pragma unroll
            for (int j = 0; j < 4; ++j) s[i][j] = 0.0f;

        for (int d = 0; d < 64; ++d) {
            float4 q4 = *(const float4*)(&Qt[d][ty * 4]);
            float4 k4 = *(const float4*)(&Kt[d][tx * 4]);
            float qr[4] = {q4.x, q4.y, q4.z, q4.w};
            float kr[4] = {k4.x, k4.y, k4.z, k4.w};
#pragma unroll
            for (int i = 0; i < 4; ++i)
#pragma unroll
                for (int j = 0; j < 4; ++j) s[i][j] += qr[i] * kr[j];
        }

        int kc[4]; int ok[4];
        const bool diag = (causal != 0) && (kt == nkt - 1);
#pragma unroll
        for (int j = 0; j < 4; ++j) {
            kc[j] = kcol0 + tx * 4 + j;
            ok[j] = kmask[b * SS + kc[j]];
        }

#pragma unroll
        for (int i = 0; i < 4; ++i) {
            const int row = row0 + ty * 4 + i;
            float mx = -INFINITY;
#pragma unroll
            for (int j = 0; j < 4; ++j) {
                const bool allow = (ok[j] != 0) && (!diag || kc[j] <= row);
                s[i][j] = allow ? s[i][j] : -INFINITY;
                mx = fmaxf(mx, s[i][j]);
            }
            mx = fmaxf(mx, __shfl_xor(mx, 1));
            mx = fmaxf(mx, __shfl_xor(mx, 2));
            mx = fmaxf(mx, __shfl_xor(mx, 4));
            mx = fmaxf(mx, __shfl_xor(mx, 8));

            const float nm = fmaxf(m[i], mx);
            if (nm > -INFINITY) {
                const float sc = __expf(m[i] - nm);
                float rs = 0.0f;
#pragma unroll
                for (int j = 0; j < 4; ++j) {
                    const float p = __expf(s[i][j] - nm);
                    s[i][j] = p;
                    rs += p;
                }
                rs += __shfl_xor(rs, 1);
                rs += __shfl_xor(rs, 2);
                rs += __shfl_xor(rs, 4);
                rs += __shfl_xor(rs, 8);
                l[i] = l[i] * sc + rs;
                m[i] = nm;
#pragma unroll
                for (int k = 0; k < 4; ++k) acc[i][k] *= sc;
            } else {
#pragma unroll
                for (int j = 0; j < 4; ++j) s[i][j] = 0.0f;
            }
        }

#pragma unroll
        for (int j = 0; j < 4; ++j) {
            *(float4*)(&Pt[tx * 4 + j][ty * 4]) =
                make_float4(s[0][j], s[1][j], s[2][j], s[3][j]);
        }
        __syncthreads();

        for (int jj = 0; jj < 64; ++jj) {
            float4 p4 = *(const float4*)(&Pt[jj][ty * 4]);
            float4 v4 = *(const float4*)(&Vs[jj][tx * 4]);
            float pr[4] = {p4.x, p4.y, p4.z, p4.w};
            float vr[4] = {v4.x, v4.y, v4.z, v4.w};
#pragma unroll
            for (int i = 0; i < 4; ++i)
#pragma unroll
                for (int k = 0; k < 4; ++k) acc[i][k] += pr[i] * vr[k];
        }
        __syncthreads();
    }

#pragma unroll
    for (int i = 0; i < 4; ++i) {
        const float inv = 1.0f / l[i];
        ushort4 o;
        o.x = f2bf(acc[i][0] * inv); o.y = f2bf(acc[i][1] * inv);
        o.z = f2bf(acc[i][2] * inv); o.w = f2bf(acc[i][3] * inv);
        *(ushort4*)(O + (size_t)(b * SS + row0 + ty * 4 + i) * DD + h * DHD + tx * 4) = o;
    }
}

// ---------------------------------------------------------------------------
// LayerNorm over last dim (768); fp32 out + optional bf16 mirror.
// ---------------------------------------------------------------------------
__global__ __launch_bounds__(256) void ln_kernel(
    const float* __restrict__ X, const float* __restrict__ gma,
    const float* __restrict__ bta, float* __restrict__ Y, u16* __restrict__ Ybf)
{
    const int row = blockIdx.x;
    const int tid = threadIdx.x;
    const float* x = X + (size_t)row * DD;

    const float v0 = x[tid], v1 = x[tid + 256], v2 = x[tid + 512];

    __shared__ float sd[256];
    sd[tid] = v0 + v1 + v2;
    __syncthreads();
    for (int off = 128; off > 0; off >>= 1) {
        if (tid < off) sd[tid] += sd[tid + off];
        __syncthreads();
    }
    const float mean = sd[0] * (1.0f / 768.0f);
    __syncthreads();

    const float q0 = v0 - mean, q1 = v1 - mean, q2 = v2 - mean;
    sd[tid] = q0 * q0 + q1 * q1 + q2 * q2;
    __syncthreads();
    for (int off = 128; off > 0; off >>= 1) {
        if (tid < off) sd[tid] += sd[tid + off];
        __syncthreads();
    }
    const float var = sd[0] * (1.0f / 768.0f);
    const float inv = rsqrtf(var + 1e-5f);

    const float y0 = q0 * inv * gma[tid]       + bta[tid];
    const float y1 = q1 * inv * gma[tid + 256] + bta[tid + 256];
    const float y2 = q2 * inv * gma[tid + 512] + bta[tid + 512];
    float* y = Y + (size_t)row * DD;
    y[tid] = y0; y[tid + 256] = y1; y[tid + 512] = y2;
    if (Ybf) {
        u16* yb = Ybf + (size_t)row * DD;
        yb[tid] = f2bf(y0); yb[tid + 256] = f2bf(y1); yb[tid + 512] = f2bf(y2);
    }
}

// ---------------------------------------------------------------------------
extern "C" void kernel_launch(void* const* d_in, const int* in_sizes, int n_in,
                              void* d_out, int out_size, void* d_ws, size_t ws_size,
                              hipStream_t stream)
{
    (void)in_sizes; (void)n_in; (void)out_size; (void)ws_size;

    const float* key_enc   = (const float*)d_in[0];
    const float* value_enc = (const float*)d_in[1];
    const float* x         = (const float*)d_in[2];
    const int*   src_mask  = (const int*)d_in[3];
    const int*   tgt_mask  = (const int*)d_in[4];
    const float* Wq_m = (const float*)d_in[5];
    const float* Wk_m = (const float*)d_in[6];
    const float* Wv_m = (const float*)d_in[7];
    const float* Wo_m = (const float*)d_in[8];
    const float* Wq_c = (const float*)d_in[9];
    const float* Wk_c = (const float*)d_in[10];
    const float* Wv_c = (const float*)d_in[11];
    const float* Wo_c = (const float*)d_in[12];
    const float* ln1_g = (const float*)d_in[13];
    const float* ln1_b = (const float*)d_in[14];
    const float* ln2_g = (const float*)d_in[15];
    const float* ln2_b = (const float*)d_in[16];
    const float* ln3_g = (const float*)d_in[17];
    const float* ln3_b = (const float*)d_in[18];
    const float* W1 = (const float*)d_in[19];
    const float* b1 = (const float*)d_in[20];
    const float* W2 = (const float*)d_in[21];
    const float* b2 = (const float*)d_in[22];

    float* out = (float*)d_out;

    // ---- workspace layout (75.5 MB) ----
    const size_t ACT = (size_t)MROWS * DD;          // 3145728 elements
    char* p = (char*)d_ws;
    u16* QKV = (u16*)p;            p += 3 * ACT * 2;        // [4096][2304] bf16
    u16* BF2 = (u16*)p;            p += ACT * 2;            // spare bf16 act
    float* T2 = (float*)p;         p += ACT * 4;
    float* Hx = (float*)p;         p += ACT * 4;
    u16* BF1 = (u16*)p;            p += ACT * 2;
    const size_t WP = (size_t)DD * DD;              // 589824
    u16* Wqm_t = (u16*)p;          p += WP * 2;
    u16* Wkm_t = (u16*)p;          p += WP * 2;
    u16* Wvm_t = (u16*)p;          p += WP * 2;
    u16* Wom_t = (u16*)p;          p += WP * 2;
    u16* Wqc_t = (u16*)p;          p += WP * 2;
    u16* Wkc_t = (u16*)p;          p += WP * 2;
    u16* Wvc_t = (u16*)p;          p += WP * 2;
    u16* Woc_t = (u16*)p;          p += WP * 2;
    u16* W1t   = (u16*)p;          p += (size_t)DD * FF * 2;
    u16* W2t   = (u16*)p;          p += (size_t)DD * FF * 2;
    u16* MID   = QKV;   // [4096][3072] bf16 aliases QKV+BF2 (dead by MLP phase)

    const dim3 blk(256);
    const int nc4 = (int)(ACT / 4);
    const dim3 gCvt(nc4 / 256);

    // ---- weight transpose+convert (Wqm/Wkm/Wvm contiguous => stacked [2304][768]) ----
    tcvt_kernel<<<dim3(2, 24, 12), blk, 0, stream>>>(Wq_m, Wqm_t, DD, DHD);
    tcvt_kernel<<<dim3(2, 24, 12), blk, 0, stream>>>(Wk_m, Wkm_t, DD, DHD);
    tcvt_kernel<<<dim3(2, 24, 12), blk, 0, stream>>>(Wv_m, Wvm_t, DD, DHD);
    tcvt_kernel<<<dim3(24, 24, 1), blk, 0, stream>>>(Wo_m, Wom_t, DD, DD);
    tcvt_kernel<<<dim3(2, 24, 12), blk, 0, stream>>>(Wq_c, Wqc_t, DD, DHD);
    tcvt_kernel<<<dim3(2, 24, 12), blk, 0, stream>>>(Wk_c, Wkc_t, DD, DHD);
    tcvt_kernel<<<dim3(2, 24, 12), blk, 0, stream>>>(Wv_c, Wvc_t, DD, DHD);
    tcvt_kernel<<<dim3(24, 24, 1), blk, 0, stream>>>(Wo_c, Woc_t, DD, DD);
    tcvt_kernel<<<dim3(96, 24, 1), blk, 0, stream>>>(W1, W1t, DD, FF);
    tcvt_kernel<<<dim3(24, 96, 1), blk, 0, stream>>>(W2, W2t, FF, DD);

    const dim3 gQKV(18, 32);   // N=2304
    const dim3 gP(6, 32);      // N=768
    const dim3 gM1(24, 32);    // N=3072
    const dim3 gAttn(16, BB * HH);

    // ---- Self-attention ----
    cvt_kernel<<<gCvt, blk, 0, stream>>>(x, BF1, nc4);
    gemm_bf16<<<gQKV, blk, 0, stream>>>(BF1, Wqm_t, MROWS, 3 * DD, DD,
                                        nullptr, nullptr, nullptr, QKV, 3 * DD, 0);
    attn_tiled_kernel<<<gAttn, blk, 0, stream>>>(QKV, QKV + DD, QKV + 2 * DD, 3 * DD,
                                                 tgt_mask, BF1, 1);
    gemm_bf16<<<gP, blk, 0, stream>>>(BF1, Wom_t, MROWS, DD, DD,
                                      nullptr, x, T2, nullptr, DD, 0);
    ln_kernel<<<MROWS, blk, 0, stream>>>(T2, ln1_g, ln1_b, Hx, BF1);

    // ---- Cross-attention ----
    gemm_bf16<<<gP, blk, 0, stream>>>(BF1, Wqc_t, MROWS, DD, DD,
                                      nullptr, nullptr, nullptr, QKV, 3 * DD, 0);
    cvt_kernel<<<gCvt, blk, 0, stream>>>(key_enc, BF2, nc4);
    gemm_bf16<<<gP, blk, 0, stream>>>(BF2, Wkc_t, MROWS, DD, DD,
                                      nullptr, nullptr, nullptr, QKV + DD, 3 * DD, 0);
    cvt_kernel<<<gCvt, blk, 0, stream>>>(value_enc, BF2, nc4);
    gemm_bf16<<<gP, blk, 0, stream>>>(BF2, Wvc_t, MROWS, DD, DD,
                                      nullptr, nullptr, nullptr, QKV + 2 * DD, 3 * DD, 0);
    attn_tiled_kernel<<<gAttn, blk, 0, stream>>>(QKV, QKV + DD, QKV + 2 * DD, 3 * DD,
                                                 src_mask, BF1, 0);
    gemm_bf16<<<gP, blk, 0, stream>>>(BF1, Woc_t, MROWS, DD, DD,
                                      nullptr, Hx, T2, nullptr, DD, 0);
    ln_kernel<<<MROWS, blk, 0, stream>>>(T2, ln2_g, ln2_b, Hx, BF1);

    // ---- MLP ----
    gemm_bf16<<<gM1, blk, 0, stream>>>(BF1, W1t, MROWS, FF, DD,
                                       b1, nullptr, nullptr, MID, FF, 1);
    gemm_bf16<<<gP, blk, 0, stream>>>(MID, W2t, MROWS, DD, FF,
                                      b2, Hx, T2, nullptr, DD, 0);
    ln_kernel<<<MROWS, blk, 0, stream>>>(T2, ln3_g, ln3_b, out, nullptr);
}

// Round 5
// 512.626 us; speedup vs baseline: 13.3172x; 1.6634x over previous
//
#include <hip/hip_runtime.h>
#include <math.h>

// Problem constants
#define BB 4
#define SS 1024
#define DD 768
#define HH 12
#define DHD 64
#define MROWS 4096
#define FF 3072

typedef unsigned short u16;
typedef float f32x4 __attribute__((ext_vector_type(4)));
typedef __bf16 bf16x8 __attribute__((ext_vector_type(8)));
typedef unsigned short u16x8 __attribute__((ext_vector_type(8)));

static __device__ __forceinline__ float bf2f(u16 u) {
    union { unsigned int i; float f; } c; c.i = ((unsigned int)u) << 16; return c.f;
}
static __device__ __forceinline__ u16 f2bf(float f) {
    union { float f; unsigned int i; } c; c.f = f;
    unsigned int i = c.i + 0x7FFFu + ((c.i >> 16) & 1u);
    return (u16)(i >> 16);
}

// ---------------------------------------------------------------------------
// bf16 MFMA GEMM: C[M,N](fp32,+bias,+gelu,+resid) and/or Cbf[M,*ldcbf](bf16)
//   A  [M,K] bf16 row-major, Bt [N,K] bf16 row-major (B transposed)
// 128x128 tile, 4 waves (2x2), each wave 64x64 = 4x4 MFMA frags, BK=32.
// ---------------------------------------------------------------------------
#define LDST 40
__global__ __launch_bounds__(256) void gemm_bf16(
    const u16* __restrict__ A, const u16* __restrict__ Bt,
    int M, int N, int K,
    const float* __restrict__ bias, const float* __restrict__ resid,
    float* __restrict__ C, u16* __restrict__ Cbf, int ldcbf, int do_gelu)
{
    __shared__ u16 As[128 * LDST];
    __shared__ u16 Bs[128 * LDST];

    const int tid  = threadIdx.x;
    const int lane = tid & 63;
    const int wave = tid >> 6;
    const int row0 = blockIdx.y * 128;
    const int col0 = blockIdx.x * 128;
    const int wm = (wave >> 1) * 64;
    const int wn = (wave & 1) * 64;

    const int srow = tid >> 1;
    const int skc  = (tid & 1) * 2;

    const u16* Ap = A  + (size_t)(row0 + srow) * K + skc * 8;
    const u16* Bp = Bt + (size_t)(col0 + srow) * K + skc * 8;
    u16* AsW = &As[srow * LDST + skc * 8];
    u16* BsW = &Bs[srow * LDST + skc * 8];

    const int fr = lane & 15;
    const int fk = (lane >> 4) * 8;
    const u16* ArP = &As[(wm + fr) * LDST + fk];
    const u16* BrP = &Bs[(wn + fr) * LDST + fk];

    f32x4 acc[4][4] = {};

    for (int k0 = 0; k0 < K; k0 += 32) {
        u16x8 a0 = *(const u16x8*)(Ap + k0);
        u16x8 a1 = *(const u16x8*)(Ap + k0 + 8);
        u16x8 b0 = *(const u16x8*)(Bp + k0);
        u16x8 b1 = *(const u16x8*)(Bp + k0 + 8);
        if (k0) __syncthreads();
        *(u16x8*)(AsW)     = a0;
        *(u16x8*)(AsW + 8) = a1;
        *(u16x8*)(BsW)     = b0;
        *(u16x8*)(BsW + 8) = b1;
        __syncthreads();

        bf16x8 af[4], bfr[4];
#pragma unroll
        for (int mi = 0; mi < 4; ++mi)
            af[mi] = __builtin_bit_cast(bf16x8, *(const u16x8*)(ArP + mi * 16 * LDST));
#pragma unroll
        for (int ni = 0; ni < 4; ++ni)
            bfr[ni] = __builtin_bit_cast(bf16x8, *(const u16x8*)(BrP + ni * 16 * LDST));
#pragma unroll
        for (int mi = 0; mi < 4; ++mi)
#pragma unroll
            for (int ni = 0; ni < 4; ++ni)
                acc[mi][ni] = __builtin_amdgcn_mfma_f32_16x16x32_bf16(
                    af[mi], bfr[ni], acc[mi][ni], 0, 0, 0);
    }

    const int orow0 = row0 + wm + (lane >> 4) * 4;
    const int ocol0 = col0 + wn + (lane & 15);
#pragma unroll
    for (int mi = 0; mi < 4; ++mi) {
#pragma unroll
        for (int ni = 0; ni < 4; ++ni) {
            const int col = ocol0 + ni * 16;
            const float bv = bias ? bias[col] : 0.0f;
#pragma unroll
            for (int r = 0; r < 4; ++r) {
                const int row = orow0 + mi * 16 + r;
                float v = acc[mi][ni][r] + bv;
                if (do_gelu) v = 0.5f * v * (1.0f + erff(v * 0.70710678118654752f));
                if (resid) v += resid[(size_t)row * N + col];
                if (C)   C[(size_t)row * N + col] = v;
                if (Cbf) Cbf[(size_t)row * ldcbf + col] = f2bf(v);
            }
        }
    }
}

// ---------------------------------------------------------------------------
// Transpose + fp32->bf16: in [K,N] fp32 (batched) -> out [N,K] bf16
// ---------------------------------------------------------------------------
__global__ __launch_bounds__(256) void tcvt_kernel(
    const float* __restrict__ in, u16* __restrict__ out, int K, int N)
{
    __shared__ float t[32][33];
    const float* ib = in + (size_t)blockIdx.z * K * N;
    u16* ob = out + (size_t)blockIdx.z * K * N;
    const int n0 = blockIdx.x * 32, k0 = blockIdx.y * 32;
    const int tx = threadIdx.x & 31, ty = threadIdx.x >> 5;
#pragma unroll
    for (int j = 0; j < 4; ++j)
        t[ty + j * 8][tx] = ib[(size_t)(k0 + ty + j * 8) * N + n0 + tx];
    __syncthreads();
#pragma unroll
    for (int j = 0; j < 4; ++j)
        ob[(size_t)(n0 + ty + j * 8) * K + k0 + tx] = f2bf(t[tx][ty + j * 8]);
}

// fp32 -> bf16 elementwise
__global__ __launch_bounds__(256) void cvt_kernel(
    const float* __restrict__ in, u16* __restrict__ out, int n4)
{
    const int i = blockIdx.x * 256 + threadIdx.x;
    if (i < n4) {
        float4 v = ((const float4*)in)[i];
        ushort4 o;
        o.x = f2bf(v.x); o.y = f2bf(v.y); o.z = f2bf(v.z); o.w = f2bf(v.w);
        ((ushort4*)out)[i] = o;
    }
}

// ---------------------------------------------------------------------------
// MFMA flash attention. One block per (64-query tile, b*h); 4 waves, each
// owning a 16-query strip. bf16 in/out, fp32 softmax.
// LDS (u16, row stride 72): Ks[key][d], Vt[d][key], Ps[q][key].
// Fragment layouts as HW-validated by gemm_bf16:
//   A/B: lane holds row/col (lane&15), 8 contiguous k at (lane>>4)*8
//   D:   col = lane&15, row = (lane>>4)*4 + reg
// ---------------------------------------------------------------------------
#define AST 72
__global__ __launch_bounds__(256) void attn_mfma_kernel(
    const u16* __restrict__ Q, const u16* __restrict__ K,
    const u16* __restrict__ V, int ldq, const int* __restrict__ kmask,
    u16* __restrict__ O, int causal)
{
    const int qt = blockIdx.x;
    const int bh = blockIdx.y;
    const int b  = bh / HH;
    const int h  = bh % HH;
    const int tid  = threadIdx.x;
    const int lane = tid & 63;
    const int w    = tid >> 6;
    const int lr = lane & 15;       // frag row/col
    const int lg = lane >> 4;       // frag k-group

    __shared__ u16 Ks[64 * AST];
    __shared__ u16 Vt[64 * AST];
    __shared__ u16 Ps[64 * AST];

    const int row0 = qt * 64;
    const int q0w  = row0 + w * 16;          // wave's query base

    // Q A-fragments: 2 k-steps (d 0..31, 32..63), loaded once from global
    bf16x8 qf[2];
    {
        const u16* qp = Q + (size_t)(b * SS + q0w + lr) * ldq + h * DHD + lg * 8;
        qf[0] = __builtin_bit_cast(bf16x8, *(const u16x8*)(qp));
        qf[1] = __builtin_bit_cast(bf16x8, *(const u16x8*)(qp + 32));
    }

    f32x4 acc[4] = {};                       // 4 d-groups of 16
    float m[4], l[4];
#pragma unroll
    for (int r = 0; r < 4; ++r) { m[r] = -INFINITY; l[r] = 0.0f; }

    const int nkt = causal ? (qt + 1) : 16;

    for (int kt = 0; kt < nkt; ++kt) {
        const int kcol0 = kt * 64;
        __syncthreads();                     // protect prior tile's Ks/Vt reads

        // ---- stage K rows [key][d]: 64 keys x 64 d, 2 chunks per thread ----
        {
            const int r = tid >> 2;
            const int c = (tid & 3) * 16;
            const u16* kp = K + (size_t)(b * SS + kcol0 + r) * ldq + h * DHD + c;
            u16x8 k0v = *(const u16x8*)(kp);
            u16x8 k1v = *(const u16x8*)(kp + 8);
            *(u16x8*)(&Ks[r * AST + c])     = k0v;
            *(u16x8*)(&Ks[r * AST + c + 8]) = k1v;
        }
        // ---- stage V transposed [d][key] ----
        {
            const int key = lane;
            const int dw  = w * 16;
            const u16* vp = V + (size_t)(b * SS + kcol0 + key) * ldq + h * DHD + dw;
            u16x8 v0 = *(const u16x8*)(vp);
            u16x8 v1 = *(const u16x8*)(vp + 8);
#pragma unroll
            for (int j = 0; j < 8; ++j) Vt[(dw + j) * AST + key] = v0[j];
#pragma unroll
            for (int j = 0; j < 8; ++j) Vt[(dw + 8 + j) * AST + key] = v1[j];
        }
        __syncthreads();

        // ---- QK^T: 4 key-groups x 2 k-steps ----
        f32x4 s[4] = {};
#pragma unroll
        for (int fi = 0; fi < 4; ++fi) {
            bf16x8 kf0 = __builtin_bit_cast(bf16x8, *(const u16x8*)(&Ks[(fi * 16 + lr) * AST + lg * 8]));
            bf16x8 kf1 = __builtin_bit_cast(bf16x8, *(const u16x8*)(&Ks[(fi * 16 + lr) * AST + 32 + lg * 8]));
            s[fi] = __builtin_amdgcn_mfma_f32_16x16x32_bf16(qf[0], kf0, s[fi], 0, 0, 0);
            s[fi] = __builtin_amdgcn_mfma_f32_16x16x32_bf16(qf[1], kf1, s[fi], 0, 0, 0);
        }

        // ---- scale + mask + online softmax (rows q0w + lg*4 + r) ----
        int okv[4];
#pragma unroll
        for (int fi = 0; fi < 4; ++fi)
            okv[fi] = kmask[b * SS + kcol0 + fi * 16 + lr];
        const bool diag = (causal != 0) && (kt == qt);

#pragma unroll
        for (int r = 0; r < 4; ++r) {
            const int qrow = q0w + lg * 4 + r;
            float sv[4];
            float mx = -INFINITY;
#pragma unroll
            for (int fi = 0; fi < 4; ++fi) {
                float v = s[fi][r] * 0.125f;
                const int key = kcol0 + fi * 16 + lr;
                const bool allow = (okv[fi] != 0) && (!diag || key <= qrow);
                v = allow ? v : -INFINITY;
                sv[fi] = v;
                mx = fmaxf(mx, v);
            }
            mx = fmaxf(mx, __shfl_xor(mx, 1));
            mx = fmaxf(mx, __shfl_xor(mx, 2));
            mx = fmaxf(mx, __shfl_xor(mx, 4));
            mx = fmaxf(mx, __shfl_xor(mx, 8));

            const float nm = fmaxf(m[r], mx);
            if (nm > -INFINITY) {
                const float rescale = __expf(m[r] - nm);
                float rs = 0.0f;
#pragma unroll
                for (int fi = 0; fi < 4; ++fi) {
                    const float pv = __expf(sv[fi] - nm);
                    sv[fi] = pv;
                    rs += pv;
                }
                rs += __shfl_xor(rs, 1);
                rs += __shfl_xor(rs, 2);
                rs += __shfl_xor(rs, 4);
                rs += __shfl_xor(rs, 8);
                l[r] = l[r] * rescale + rs;
                m[r] = nm;
#pragma unroll
                for (int di = 0; di < 4; ++di) acc[di][r] *= rescale;
            } else {
#pragma unroll
                for (int fi = 0; fi < 4; ++fi) sv[fi] = 0.0f;
            }
            // write P row (wave-private strip; no barrier needed)
#pragma unroll
            for (int fi = 0; fi < 4; ++fi)
                Ps[(w * 16 + lg * 4 + r) * AST + fi * 16 + lr] = f2bf(sv[fi]);
        }

        // ---- PV: A = Ps (own strip), B = Vt ----
#pragma unroll
        for (int kk = 0; kk < 2; ++kk) {
            bf16x8 pf = __builtin_bit_cast(bf16x8, *(const u16x8*)(&Ps[(w * 16 + lr) * AST + kk * 32 + lg * 8]));
#pragma unroll
            for (int di = 0; di < 4; ++di) {
                bf16x8 vf = __builtin_bit_cast(bf16x8, *(const u16x8*)(&Vt[(di * 16 + lr) * AST + kk * 32 + lg * 8]));
                acc[di] = __builtin_amdgcn_mfma_f32_16x16x32_bf16(pf, vf, acc[di], 0, 0, 0);
            }
        }
    }

    // ---- epilogue: O = acc / l ----
#pragma unroll
    for (int r = 0; r < 4; ++r) {
        const float inv = (l[r] > 0.0f) ? (1.0f / l[r]) : 0.0f;
        const size_t orow = (size_t)(b * SS + q0w + lg * 4 + r) * DD + h * DHD;
#pragma unroll
        for (int di = 0; di < 4; ++di)
            O[orow + di * 16 + lr] = f2bf(acc[di][r] * inv);
    }
}

// ---------------------------------------------------------------------------
// LayerNorm over last dim (768); fp32 out + optional bf16 mirror.
// ---------------------------------------------------------------------------
__global__ __launch_bounds__(256) void ln_kernel(
    const float* __restrict__ X, const float* __restrict__ gma,
    const float* __restrict__ bta, float* __restrict__ Y, u16* __restrict__ Ybf)
{
    const int row = blockIdx.x;
    const int tid = threadIdx.x;
    const float* x = X + (size_t)row * DD;

    const float v0 = x[tid], v1 = x[tid + 256], v2 = x[tid + 512];

    __shared__ float sd[256];
    sd[tid] = v0 + v1 + v2;
    __syncthreads();
    for (int off = 128; off > 0; off >>= 1) {
        if (tid < off) sd[tid] += sd[tid + off];
        __syncthreads();
    }
    const float mean = sd[0] * (1.0f / 768.0f);
    __syncthreads();

    const float q0 = v0 - mean, q1 = v1 - mean, q2 = v2 - mean;
    sd[tid] = q0 * q0 + q1 * q1 + q2 * q2;
    __syncthreads();
    for (int off = 128; off > 0; off >>= 1) {
        if (tid < off) sd[tid] += sd[tid + off];
        __syncthreads();
    }
    const float var = sd[0] * (1.0f / 768.0f);
    const float inv = rsqrtf(var + 1e-5f);

    const float y0 = q0 * inv * gma[tid]       + bta[tid];
    const float y1 = q1 * inv * gma[tid + 256] + bta[tid + 256];
    const float y2 = q2 * inv * gma[tid + 512] + bta[tid + 512];
    float* y = Y + (size_t)row * DD;
    y[tid] = y0; y[tid + 256] = y1; y[tid + 512] = y2;
    if (Ybf) {
        u16* yb = Ybf + (size_t)row * DD;
        yb[tid] = f2bf(y0); yb[tid + 256] = f2bf(y1); yb[tid + 512] = f2bf(y2);
    }
}

// ---------------------------------------------------------------------------
extern "C" void kernel_launch(void* const* d_in, const int* in_sizes, int n_in,
                              void* d_out, int out_size, void* d_ws, size_t ws_size,
                              hipStream_t stream)
{
    (void)in_sizes; (void)n_in; (void)out_size; (void)ws_size;

    const float* key_enc   = (const float*)d_in[0];
    const float* value_enc = (const float*)d_in[1];
    const float* x         = (const float*)d_in[2];
    const int*   src_mask  = (const int*)d_in[3];
    const int*   tgt_mask  = (const int*)d_in[4];
    const float* Wq_m = (const float*)d_in[5];
    const float* Wk_m = (const float*)d_in[6];
    const float* Wv_m = (const float*)d_in[7];
    const float* Wo_m = (const float*)d_in[8];
    const float* Wq_c = (const float*)d_in[9];
    const float* Wk_c = (const float*)d_in[10];
    const float* Wv_c = (const float*)d_in[11];
    const float* Wo_c = (const float*)d_in[12];
    const float* ln1_g = (const float*)d_in[13];
    const float* ln1_b = (const float*)d_in[14];
    const float* ln2_g = (const float*)d_in[15];
    const float* ln2_b = (const float*)d_in[16];
    const float* ln3_g = (const float*)d_in[17];
    const float* ln3_b = (const float*)d_in[18];
    const float* W1 = (const float*)d_in[19];
    const float* b1 = (const float*)d_in[20];
    const float* W2 = (const float*)d_in[21];
    const float* b2 = (const float*)d_in[22];

    float* out = (float*)d_out;

    const size_t ACT = (size_t)MROWS * DD;
    char* p = (char*)d_ws;
    u16* QKV = (u16*)p;            p += 3 * ACT * 2;        // [4096][2304] bf16
    u16* BF2 = (u16*)p;            p += ACT * 2;
    float* T2 = (float*)p;         p += ACT * 4;
    float* Hx = (float*)p;         p += ACT * 4;
    u16* BF1 = (u16*)p;            p += ACT * 2;
    const size_t WP = (size_t)DD * DD;
    u16* Wqm_t = (u16*)p;          p += WP * 2;
    u16* Wkm_t = (u16*)p;          p += WP * 2;
    u16* Wvm_t = (u16*)p;          p += WP * 2;
    u16* Wom_t = (u16*)p;          p += WP * 2;
    u16* Wqc_t = (u16*)p;          p += WP * 2;
    u16* Wkc_t = (u16*)p;          p += WP * 2;
    u16* Wvc_t = (u16*)p;          p += WP * 2;
    u16* Woc_t = (u16*)p;          p += WP * 2;
    u16* W1t   = (u16*)p;          p += (size_t)DD * FF * 2;
    u16* W2t   = (u16*)p;          p += (size_t)DD * FF * 2;
    u16* MID   = QKV;   // [4096][3072] bf16 aliases QKV+BF2 (dead by MLP phase)

    const dim3 blk(256);
    const int nc4 = (int)(ACT / 4);
    const dim3 gCvt(nc4 / 256);

    tcvt_kernel<<<dim3(2, 24, 12), blk, 0, stream>>>(Wq_m, Wqm_t, DD, DHD);
    tcvt_kernel<<<dim3(2, 24, 12), blk, 0, stream>>>(Wk_m, Wkm_t, DD, DHD);
    tcvt_kernel<<<dim3(2, 24, 12), blk, 0, stream>>>(Wv_m, Wvm_t, DD, DHD);
    tcvt_kernel<<<dim3(24, 24, 1), blk, 0, stream>>>(Wo_m, Wom_t, DD, DD);
    tcvt_kernel<<<dim3(2, 24, 12), blk, 0, stream>>>(Wq_c, Wqc_t, DD, DHD);
    tcvt_kernel<<<dim3(2, 24, 12), blk, 0, stream>>>(Wk_c, Wkc_t, DD, DHD);
    tcvt_kernel<<<dim3(2, 24, 12), blk, 0, stream>>>(Wv_c, Wvc_t, DD, DHD);
    tcvt_kernel<<<dim3(24, 24, 1), blk, 0, stream>>>(Wo_c, Woc_t, DD, DD);
    tcvt_kernel<<<dim3(96, 24, 1), blk, 0, stream>>>(W1, W1t, DD, FF);
    tcvt_kernel<<<dim3(24, 96, 1), blk, 0, stream>>>(W2, W2t, FF, DD);

    const dim3 gQKV(18, 32);   // N=2304
    const dim3 gP(6, 32);      // N=768
    const dim3 gM1(24, 32);    // N=3072
    const dim3 gAttn(16, BB * HH);

    // ---- Self-attention ----
    cvt_kernel<<<gCvt, blk, 0, stream>>>(x, BF1, nc4);
    gemm_bf16<<<gQKV, blk, 0, stream>>>(BF1, Wqm_t, MROWS, 3 * DD, DD,
                                        nullptr, nullptr, nullptr, QKV, 3 * DD, 0);
    attn_mfma_kernel<<<gAttn, blk, 0, stream>>>(QKV, QKV + DD, QKV + 2 * DD, 3 * DD,
                                                tgt_mask, BF1, 1);
    gemm_bf16<<<gP, blk, 0, stream>>>(BF1, Wom_t, MROWS, DD, DD,
                                      nullptr, x, T2, nullptr, DD, 0);
    ln_kernel<<<MROWS, blk, 0, stream>>>(T2, ln1_g, ln1_b, Hx, BF1);

    // ---- Cross-attention ----
    gemm_bf16<<<gP, blk, 0, stream>>>(BF1, Wqc_t, MROWS, DD, DD,
                                      nullptr, nullptr, nullptr, QKV, 3 * DD, 0);
    cvt_kernel<<<gCvt, blk, 0, stream>>>(key_enc, BF2, nc4);
    gemm_bf16<<<gP, blk, 0, stream>>>(BF2, Wkc_t, MROWS, DD, DD,
                                      nullptr, nullptr, nullptr, QKV + DD, 3 * DD, 0);
    cvt_kernel<<<gCvt, blk, 0, stream>>>(value_enc, BF2, nc4);
    gemm_bf16<<<gP, blk, 0, stream>>>(BF2, Wvc_t, MROWS, DD, DD,
                                      nullptr, nullptr, nullptr, QKV + 2 * DD, 3 * DD, 0);
    attn_mfma_kernel<<<gAttn, blk, 0, stream>>>(QKV, QKV + DD, QKV + 2 * DD, 3 * DD,
                                                src_mask, BF1, 0);
    gemm_bf16<<<gP, blk, 0, stream>>>(BF1, Woc_t, MROWS, DD, DD,
                                      nullptr, Hx, T2, nullptr, DD, 0);
    ln_kernel<<<MROWS, blk, 0, stream>>>(T2, ln2_g, ln2_b, Hx, BF1);

    // ---- MLP ----
    gemm_bf16<<<gM1, blk, 0, stream>>>(BF1, W1t, MROWS, FF, DD,
                                       b1, nullptr, nullptr, MID, FF, 1);
    gemm_bf16<<<gP, blk, 0, stream>>>(MID, W2t, MROWS, DD, FF,
                                      b2, Hx, T2, nullptr, DD, 0);
    ln_kernel<<<MROWS, blk, 0, stream>>>(T2, ln3_g, ln3_b, out, nullptr);
}

// Round 6
// 405.036 us; speedup vs baseline: 16.8546x; 1.2656x over previous
//
#include <hip/hip_runtime.h>
#include <math.h>

// Problem constants
#define BB 4
#define SS 1024
#define DD 768
#define HH 12
#define DHD 64
#define MROWS 4096
#define FF 3072

typedef unsigned short u16;
typedef float f32x4 __attribute__((ext_vector_type(4)));
typedef __bf16 bf16x8 __attribute__((ext_vector_type(8)));
typedef unsigned short u16x8 __attribute__((ext_vector_type(8)));

static __device__ __forceinline__ float bf2f(u16 u) {
    union { unsigned int i; float f; } c; c.i = ((unsigned int)u) << 16; return c.f;
}
static __device__ __forceinline__ u16 f2bf(float f) {
    union { float f; unsigned int i; } c; c.f = f;
    unsigned int i = c.i + 0x7FFFu + ((c.i >> 16) & 1u);
    return (u16)(i >> 16);
}

// ---------------------------------------------------------------------------
// bf16 MFMA GEMM core. BM=64 x BN=128 tile, BK=32, 256 threads = 4 waves
// (2x2), each wave 32x64 = 2x4 MFMA frags. Register prefetch of next K-tile.
//   A  [M,K] bf16 row-major, Bt [N,K] bf16 row-major (B transposed)
// Outputs: C fp32 [M,N] (optional), Cbf bf16 [M,ldcbf] at col offset cboff
// (optional). resid: fp32 or bf16 (at most one non-null), indexed [row*N+col].
// ---------------------------------------------------------------------------
#define LDST 40
static __device__ __forceinline__ void gemm64_core(
    const u16* __restrict__ A, const u16* __restrict__ Bt,
    int N, int K,
    const float* __restrict__ bias,
    const float* __restrict__ residf, const u16* __restrict__ residb,
    float* __restrict__ C, u16* __restrict__ Cbf, int ldcbf, int cboff,
    int do_gelu, int row0, int col0, u16* As, u16* Bs)
{
    const int tid  = threadIdx.x;
    const int lane = tid & 63;
    const int w    = tid >> 6;
    const int wm = (w >> 1) * 32;
    const int wn = (w & 1) * 64;

    // staging: A 64x32 (8 elems/thread), B 128x32 (16 elems/thread)
    const int arow = tid >> 2;
    const int akc  = (tid & 3) * 8;
    const int brow = tid >> 1;
    const int bkc  = (tid & 1) * 16;

    const u16* Ap = A  + (size_t)(row0 + arow) * K + akc;
    const u16* Bp = Bt + (size_t)(col0 + brow) * K + bkc;
    u16* AsW = &As[arow * LDST + akc];
    u16* BsW = &Bs[brow * LDST + bkc];

    const int fr = lane & 15;
    const int fk = (lane >> 4) * 8;

    f32x4 acc[2][4] = {};

    u16x8 ar  = *(const u16x8*)(Ap);
    u16x8 br0 = *(const u16x8*)(Bp);
    u16x8 br1 = *(const u16x8*)(Bp + 8);

    for (int k0 = 0; k0 < K; k0 += 32) {
        if (k0) __syncthreads();
        *(u16x8*)AsW       = ar;
        *(u16x8*)BsW       = br0;
        *(u16x8*)(BsW + 8) = br1;
        __syncthreads();

        if (k0 + 32 < K) {                  // prefetch next tile into regs
            ar  = *(const u16x8*)(Ap + k0 + 32);
            br0 = *(const u16x8*)(Bp + k0 + 32);
            br1 = *(const u16x8*)(Bp + k0 + 40);
        }

        bf16x8 af[2], bfv[4];
#pragma unroll
        for (int mi = 0; mi < 2; ++mi)
            af[mi] = __builtin_bit_cast(bf16x8,
                *(const u16x8*)(&As[(wm + 16 * mi + fr) * LDST + fk]));
#pragma unroll
        for (int ni = 0; ni < 4; ++ni)
            bfv[ni] = __builtin_bit_cast(bf16x8,
                *(const u16x8*)(&Bs[(wn + 16 * ni + fr) * LDST + fk]));
#pragma unroll
        for (int mi = 0; mi < 2; ++mi)
#pragma unroll
            for (int ni = 0; ni < 4; ++ni)
                acc[mi][ni] = __builtin_amdgcn_mfma_f32_16x16x32_bf16(
                    af[mi], bfv[ni], acc[mi][ni], 0, 0, 0);
    }

    // Epilogue. D layout: col = lane&15, row = (lane>>4)*4 + reg
    const int orow0 = row0 + wm + (lane >> 4) * 4;
    const int ocol0 = col0 + wn + fr;
#pragma unroll
    for (int mi = 0; mi < 2; ++mi) {
#pragma unroll
        for (int ni = 0; ni < 4; ++ni) {
            const int col = ocol0 + ni * 16;
            const float bv = bias ? bias[col] : 0.0f;
#pragma unroll
            for (int r = 0; r < 4; ++r) {
                const int row = orow0 + mi * 16 + r;
                float v = acc[mi][ni][r] + bv;
                if (do_gelu) v = 0.5f * v * (1.0f + erff(v * 0.70710678118654752f));
                if (residf) v += residf[(size_t)row * N + col];
                if (residb) v += bf2f(residb[(size_t)row * N + col]);
                if (C)   C[(size_t)row * N + col] = v;
                if (Cbf) Cbf[(size_t)row * ldcbf + cboff + col] = f2bf(v);
            }
        }
    }
}

__global__ __launch_bounds__(256) void gemm64(
    const u16* __restrict__ A, const u16* __restrict__ Bt, int N, int K,
    const float* __restrict__ bias,
    const float* __restrict__ residf, const u16* __restrict__ residb,
    float* __restrict__ C, u16* __restrict__ Cbf, int ldcbf, int do_gelu)
{
    __shared__ u16 As[64 * LDST];
    __shared__ u16 Bs[128 * LDST];
    gemm64_core(A, Bt, N, K, bias, residf, residb, C, Cbf, ldcbf, 0, do_gelu,
                blockIdx.y * 64, blockIdx.x * 128, As, Bs);
}

// Batched 3-way projection (cross-attn Q/K/V): z selects (A,B), output goes
// to bf16 QKV at column offset z*768. N=K=768.
__global__ __launch_bounds__(256) void gemm64_qkv3(
    const u16* __restrict__ A0, const u16* __restrict__ A1, const u16* __restrict__ A2,
    const u16* __restrict__ B0, const u16* __restrict__ B1, const u16* __restrict__ B2,
    u16* __restrict__ Cbf, int ldcbf)
{
    __shared__ u16 As[64 * LDST];
    __shared__ u16 Bs[128 * LDST];
    const int z = blockIdx.z;
    const u16* A = (z == 0) ? A0 : (z == 1) ? A1 : A2;
    const u16* B = (z == 0) ? B0 : (z == 1) ? B1 : B2;
    gemm64_core(A, B, DD, DD, nullptr, nullptr, nullptr, nullptr, Cbf, ldcbf,
                z * DD, 0, blockIdx.y * 64, blockIdx.x * 128, As, Bs);
}

// ---------------------------------------------------------------------------
// Transpose + fp32->bf16: in [K,N] fp32 (z-batched) -> out [N,K] bf16
// ---------------------------------------------------------------------------
__global__ __launch_bounds__(256) void tcvt_kernel(
    const float* __restrict__ in, u16* __restrict__ out, int K, int N)
{
    __shared__ float t[32][33];
    const float* ib = in + (size_t)blockIdx.z * K * N;
    u16* ob = out + (size_t)blockIdx.z * K * N;
    const int n0 = blockIdx.x * 32, k0 = blockIdx.y * 32;
    const int tx = threadIdx.x & 31, ty = threadIdx.x >> 5;
#pragma unroll
    for (int j = 0; j < 4; ++j)
        t[ty + j * 8][tx] = ib[(size_t)(k0 + ty + j * 8) * N + n0 + tx];
    __syncthreads();
#pragma unroll
    for (int j = 0; j < 4; ++j)
        ob[(size_t)(n0 + ty + j * 8) * K + k0 + tx] = f2bf(t[tx][ty + j * 8]);
}

// Six per-head weights [12,768,64] -> [768,768] each, stacked into Wm6.
// z in [0,72): wi = z/12 (weight), head = z%12. Per-head: K=768, N=64.
__global__ __launch_bounds__(256) void tcvt6_kernel(
    const float* __restrict__ w0, const float* __restrict__ w1,
    const float* __restrict__ w2, const float* __restrict__ w3,
    const float* __restrict__ w4, const float* __restrict__ w5,
    u16* __restrict__ Wm6)
{
    __shared__ float t[32][33];
    const int z = blockIdx.z;
    const int wi = z / 12, head = z % 12;
    const float* wsel = (wi == 0) ? w0 : (wi == 1) ? w1 : (wi == 2) ? w2 :
                        (wi == 3) ? w3 : (wi == 4) ? w4 : w5;
    const float* ib = wsel + (size_t)head * DD * DHD;
    u16* ob = Wm6 + (size_t)wi * DD * DD + (size_t)head * DHD * DD;
    const int n0 = blockIdx.x * 32, k0 = blockIdx.y * 32;
    const int tx = threadIdx.x & 31, ty = threadIdx.x >> 5;
#pragma unroll
    for (int j = 0; j < 4; ++j)
        t[ty + j * 8][tx] = ib[(size_t)(k0 + ty + j * 8) * DHD + n0 + tx];
    __syncthreads();
#pragma unroll
    for (int j = 0; j < 4; ++j)
        ob[(size_t)(n0 + ty + j * 8) * DD + k0 + tx] = f2bf(t[tx][ty + j * 8]);
}

// fp32 -> bf16 elementwise, 3 tensors batched over z
__global__ __launch_bounds__(256) void cvt3_kernel(
    const float* __restrict__ s0, const float* __restrict__ s1,
    const float* __restrict__ s2,
    u16* __restrict__ d0, u16* __restrict__ d1, u16* __restrict__ d2, int n4)
{
    const int z = blockIdx.z;
    const float* s = (z == 0) ? s0 : (z == 1) ? s1 : s2;
    u16* d = (z == 0) ? d0 : (z == 1) ? d1 : d2;
    const int i = blockIdx.x * 256 + threadIdx.x;
    if (i < n4) {
        float4 v = ((const float4*)s)[i];
        ushort4 o;
        o.x = f2bf(v.x); o.y = f2bf(v.y); o.z = f2bf(v.z); o.w = f2bf(v.w);
        ((ushort4*)d)[i] = o;
    }
}

// ---------------------------------------------------------------------------
// MFMA flash attention (validated R4). One block per (64-query tile, b*h);
// 4 waves, each a 16-query strip. bf16 in/out, fp32 softmax.
// ---------------------------------------------------------------------------
#define AST 72
__global__ __launch_bounds__(256) void attn_mfma_kernel(
    const u16* __restrict__ Q, const u16* __restrict__ K,
    const u16* __restrict__ V, int ldq, const int* __restrict__ kmask,
    u16* __restrict__ O, int causal)
{
    const int qt = blockIdx.x;
    const int bh = blockIdx.y;
    const int b  = bh / HH;
    const int h  = bh % HH;
    const int tid  = threadIdx.x;
    const int lane = tid & 63;
    const int w    = tid >> 6;
    const int lr = lane & 15;
    const int lg = lane >> 4;

    __shared__ u16 Ks[64 * AST];
    __shared__ u16 Vt[64 * AST];
    __shared__ u16 Ps[64 * AST];

    const int row0 = qt * 64;
    const int q0w  = row0 + w * 16;

    bf16x8 qf[2];
    {
        const u16* qp = Q + (size_t)(b * SS + q0w + lr) * ldq + h * DHD + lg * 8;
        qf[0] = __builtin_bit_cast(bf16x8, *(const u16x8*)(qp));
        qf[1] = __builtin_bit_cast(bf16x8, *(const u16x8*)(qp + 32));
    }

    f32x4 acc[4] = {};
    float m[4], l[4];
#pragma unroll
    for (int r = 0; r < 4; ++r) { m[r] = -INFINITY; l[r] = 0.0f; }

    const int nkt = causal ? (qt + 1) : 16;

    for (int kt = 0; kt < nkt; ++kt) {
        const int kcol0 = kt * 64;
        __syncthreads();

        {
            const int r = tid >> 2;
            const int c = (tid & 3) * 16;
            const u16* kp = K + (size_t)(b * SS + kcol0 + r) * ldq + h * DHD + c;
            u16x8 k0v = *(const u16x8*)(kp);
            u16x8 k1v = *(const u16x8*)(kp + 8);
            *(u16x8*)(&Ks[r * AST + c])     = k0v;
            *(u16x8*)(&Ks[r * AST + c + 8]) = k1v;
        }
        {
            const int key = lane;
            const int dw  = w * 16;
            const u16* vp = V + (size_t)(b * SS + kcol0 + key) * ldq + h * DHD + dw;
            u16x8 v0 = *(const u16x8*)(vp);
            u16x8 v1 = *(const u16x8*)(vp + 8);
#pragma unroll
            for (int j = 0; j < 8; ++j) Vt[(dw + j) * AST + key] = v0[j];
#pragma unroll
            for (int j = 0; j < 8; ++j) Vt[(dw + 8 + j) * AST + key] = v1[j];
        }
        __syncthreads();

        f32x4 s[4] = {};
#pragma unroll
        for (int fi = 0; fi < 4; ++fi) {
            bf16x8 kf0 = __builtin_bit_cast(bf16x8, *(const u16x8*)(&Ks[(fi * 16 + lr) * AST + lg * 8]));
            bf16x8 kf1 = __builtin_bit_cast(bf16x8, *(const u16x8*)(&Ks[(fi * 16 + lr) * AST + 32 + lg * 8]));
            s[fi] = __builtin_amdgcn_mfma_f32_16x16x32_bf16(qf[0], kf0, s[fi], 0, 0, 0);
            s[fi] = __builtin_amdgcn_mfma_f32_16x16x32_bf16(qf[1], kf1, s[fi], 0, 0, 0);
        }

        int okv[4];
#pragma unroll
        for (int fi = 0; fi < 4; ++fi)
            okv[fi] = kmask[b * SS + kcol0 + fi * 16 + lr];
        const bool diag = (causal != 0) && (kt == qt);

#pragma unroll
        for (int r = 0; r < 4; ++r) {
            const int qrow = q0w + lg * 4 + r;
            float sv[4];
            float mx = -INFINITY;
#pragma unroll
            for (int fi = 0; fi < 4; ++fi) {
                float v = s[fi][r] * 0.125f;
                const int key = kcol0 + fi * 16 + lr;
                const bool allow = (okv[fi] != 0) && (!diag || key <= qrow);
                v = allow ? v : -INFINITY;
                sv[fi] = v;
                mx = fmaxf(mx, v);
            }
            mx = fmaxf(mx, __shfl_xor(mx, 1));
            mx = fmaxf(mx, __shfl_xor(mx, 2));
            mx = fmaxf(mx, __shfl_xor(mx, 4));
            mx = fmaxf(mx, __shfl_xor(mx, 8));

            const float nm = fmaxf(m[r], mx);
            if (nm > -INFINITY) {
                const float rescale = __expf(m[r] - nm);
                float rs = 0.0f;
#pragma unroll
                for (int fi = 0; fi < 4; ++fi) {
                    const float pv = __expf(sv[fi] - nm);
                    sv[fi] = pv;
                    rs += pv;
                }
                rs += __shfl_xor(rs, 1);
                rs += __shfl_xor(rs, 2);
                rs += __shfl_xor(rs, 4);
                rs += __shfl_xor(rs, 8);
                l[r] = l[r] * rescale + rs;
                m[r] = nm;
#pragma unroll
                for (int di = 0; di < 4; ++di) acc[di][r] *= rescale;
            } else {
#pragma unroll
                for (int fi = 0; fi < 4; ++fi) sv[fi] = 0.0f;
            }
#pragma unroll
            for (int fi = 0; fi < 4; ++fi)
                Ps[(w * 16 + lg * 4 + r) * AST + fi * 16 + lr] = f2bf(sv[fi]);
        }

#pragma unroll
        for (int kk = 0; kk < 2; ++kk) {
            bf16x8 pf = __builtin_bit_cast(bf16x8, *(const u16x8*)(&Ps[(w * 16 + lr) * AST + kk * 32 + lg * 8]));
#pragma unroll
            for (int di = 0; di < 4; ++di) {
                bf16x8 vf = __builtin_bit_cast(bf16x8, *(const u16x8*)(&Vt[(di * 16 + lr) * AST + kk * 32 + lg * 8]));
                acc[di] = __builtin_amdgcn_mfma_f32_16x16x32_bf16(pf, vf, acc[di], 0, 0, 0);
            }
        }
    }

#pragma unroll
    for (int r = 0; r < 4; ++r) {
        const float inv = (l[r] > 0.0f) ? (1.0f / l[r]) : 0.0f;
        const size_t orow = (size_t)(b * SS + q0w + lg * 4 + r) * DD + h * DHD;
#pragma unroll
        for (int di = 0; di < 4; ++di)
            O[orow + di * 16 + lr] = f2bf(acc[di][r] * inv);
    }
}

// ---------------------------------------------------------------------------
// LayerNorm over last dim (768); nullable fp32 out / bf16 out.
// ---------------------------------------------------------------------------
__global__ __launch_bounds__(256) void ln_kernel(
    const float* __restrict__ X, const float* __restrict__ gma,
    const float* __restrict__ bta, float* __restrict__ Y, u16* __restrict__ Ybf)
{
    const int row = blockIdx.x;
    const int tid = threadIdx.x;
    const float* x = X + (size_t)row * DD;

    const float v0 = x[tid], v1 = x[tid + 256], v2 = x[tid + 512];

    __shared__ float sd[256];
    sd[tid] = v0 + v1 + v2;
    __syncthreads();
    for (int off = 128; off > 0; off >>= 1) {
        if (tid < off) sd[tid] += sd[tid + off];
        __syncthreads();
    }
    const float mean = sd[0] * (1.0f / 768.0f);
    __syncthreads();

    const float q0 = v0 - mean, q1 = v1 - mean, q2 = v2 - mean;
    sd[tid] = q0 * q0 + q1 * q1 + q2 * q2;
    __syncthreads();
    for (int off = 128; off > 0; off >>= 1) {
        if (tid < off) sd[tid] += sd[tid + off];
        __syncthreads();
    }
    const float var = sd[0] * (1.0f / 768.0f);
    const float inv = rsqrtf(var + 1e-5f);

    const float y0 = q0 * inv * gma[tid]       + bta[tid];
    const float y1 = q1 * inv * gma[tid + 256] + bta[tid + 256];
    const float y2 = q2 * inv * gma[tid + 512] + bta[tid + 512];
    if (Y) {
        float* y = Y + (size_t)row * DD;
        y[tid] = y0; y[tid + 256] = y1; y[tid + 512] = y2;
    }
    if (Ybf) {
        u16* yb = Ybf + (size_t)row * DD;
        yb[tid] = f2bf(y0); yb[tid + 256] = f2bf(y1); yb[tid + 512] = f2bf(y2);
    }
}

// ---------------------------------------------------------------------------
extern "C" void kernel_launch(void* const* d_in, const int* in_sizes, int n_in,
                              void* d_out, int out_size, void* d_ws, size_t ws_size,
                              hipStream_t stream)
{
    (void)in_sizes; (void)n_in; (void)out_size; (void)ws_size;

    const float* key_enc   = (const float*)d_in[0];
    const float* value_enc = (const float*)d_in[1];
    const float* x         = (const float*)d_in[2];
    const int*   src_mask  = (const int*)d_in[3];
    const int*   tgt_mask  = (const int*)d_in[4];
    const float* Wq_m = (const float*)d_in[5];
    const float* Wk_m = (const float*)d_in[6];
    const float* Wv_m = (const float*)d_in[7];
    const float* Wo_m = (const float*)d_in[8];
    const float* Wq_c = (const float*)d_in[9];
    const float* Wk_c = (const float*)d_in[10];
    const float* Wv_c = (const float*)d_in[11];
    const float* Wo_c = (const float*)d_in[12];
    const float* ln1_g = (const float*)d_in[13];
    const float* ln1_b = (const float*)d_in[14];
    const float* ln2_g = (const float*)d_in[15];
    const float* ln2_b = (const float*)d_in[16];
    const float* ln3_g = (const float*)d_in[17];
    const float* ln3_b = (const float*)d_in[18];
    const float* W1 = (const float*)d_in[19];
    const float* b1 = (const float*)d_in[20];
    const float* W2 = (const float*)d_in[21];
    const float* b2 = (const float*)d_in[22];

    float* out = (float*)d_out;

    // ---- workspace layout (~82 MB) ----
    const size_t ACT = (size_t)MROWS * DD;          // 3145728
    const size_t WP  = (size_t)DD * DD;             // 589824
    char* p = (char*)d_ws;
    u16* QKV  = (u16*)p;   p += 3 * ACT * 2;        // [4096][2304] bf16
    u16* BFx  = (u16*)p;   p += ACT * 2;            // x bf16 (MID tail)
    u16* BFK  = (u16*)p;   p += ACT * 2;            // key_enc bf16
    u16* BFV  = (u16*)p;   p += ACT * 2;            // value_enc bf16
    u16* BF1a = (u16*)p;   p += ACT * 2;            // attention outputs
    u16* BF1h = (u16*)p;   p += ACT * 2;            // h / h2 bf16
    float* T2 = (float*)p; p += ACT * 4;            // pre-LN fp32
    u16* Wm6  = (u16*)p;   p += 6 * WP * 2;         // q_m,k_m,v_m,q_c,k_c,v_c [768][768] each
    u16* Wom_t = (u16*)p;  p += WP * 2;
    u16* Woc_t = (u16*)p;  p += WP * 2;
    u16* W1t  = (u16*)p;   p += (size_t)DD * FF * 2;
    u16* W2t  = (u16*)p;   p += (size_t)DD * FF * 2;
    u16* MID  = QKV;       // [4096][3072] bf16 aliases QKV+BFx (dead by MLP)

    const dim3 blk(256);
    const int nc4 = (int)(ACT / 4);

    // ---- prep: converts + weight transposes (6 dispatches) ----
    cvt3_kernel<<<dim3(nc4 / 256, 1, 3), blk, 0, stream>>>(
        x, key_enc, value_enc, BFx, BFK, BFV, nc4);
    tcvt6_kernel<<<dim3(2, 24, 72), blk, 0, stream>>>(
        Wq_m, Wk_m, Wv_m, Wq_c, Wk_c, Wv_c, Wm6);
    tcvt_kernel<<<dim3(24, 24, 1), blk, 0, stream>>>(Wo_m, Wom_t, DD, DD);
    tcvt_kernel<<<dim3(24, 24, 1), blk, 0, stream>>>(Wo_c, Woc_t, DD, DD);
    tcvt_kernel<<<dim3(96, 24, 1), blk, 0, stream>>>(W1, W1t, DD, FF);
    tcvt_kernel<<<dim3(24, 96, 1), blk, 0, stream>>>(W2, W2t, FF, DD);

    const dim3 gQKV(18, 64);     // N=2304, 1152 blocks
    const dim3 gP(6, 64);        // N=768,  384 blocks
    const dim3 gP3(6, 64, 3);    // cross projections, 1152 blocks
    const dim3 gM1(24, 64);      // N=3072, 1536 blocks
    const dim3 gAttn(16, BB * HH);

    // ---- Self-attention ----
    gemm64<<<gQKV, blk, 0, stream>>>(BFx, Wm6, 3 * DD, DD,
                                     nullptr, nullptr, nullptr,
                                     nullptr, QKV, 3 * DD, 0);
    attn_mfma_kernel<<<gAttn, blk, 0, stream>>>(QKV, QKV + DD, QKV + 2 * DD, 3 * DD,
                                                tgt_mask, BF1a, 1);
    gemm64<<<gP, blk, 0, stream>>>(BF1a, Wom_t, DD, DD,
                                   nullptr, x, nullptr,
                                   T2, nullptr, DD, 0);
    ln_kernel<<<MROWS, blk, 0, stream>>>(T2, ln1_g, ln1_b, nullptr, BF1h);

    // ---- Cross-attention ----
    gemm64_qkv3<<<gP3, blk, 0, stream>>>(BF1h, BFK, BFV,
                                         Wm6 + 3 * WP, Wm6 + 4 * WP, Wm6 + 5 * WP,
                                         QKV, 3 * DD);
    attn_mfma_kernel<<<gAttn, blk, 0, stream>>>(QKV, QKV + DD, QKV + 2 * DD, 3 * DD,
                                                src_mask, BF1a, 0);
    gemm64<<<gP, blk, 0, stream>>>(BF1a, Woc_t, DD, DD,
                                   nullptr, nullptr, BF1h,
                                   T2, nullptr, DD, 0);
    ln_kernel<<<MROWS, blk, 0, stream>>>(T2, ln2_g, ln2_b, nullptr, BF1h);

    // ---- MLP ----
    gemm64<<<gM1, blk, 0, stream>>>(BF1h, W1t, FF, DD,
                                    b1, nullptr, nullptr,
                                    nullptr, MID, FF, 1);
    gemm64<<<gP, blk, 0, stream>>>(MID, W2t, DD, FF,
                                   b2, nullptr, BF1h,
                                   T2, nullptr, DD, 0);
    ln_kernel<<<MROWS, blk, 0, stream>>>(T2, ln3_g, ln3_b, out, nullptr);
}

// Round 7
// 404.120 us; speedup vs baseline: 16.8929x; 1.0023x over previous
//
#include <hip/hip_runtime.h>
#include <math.h>

// Problem constants
#define BB 4
#define SS 1024
#define DD 768
#define HH 12
#define DHD 64
#define MROWS 4096
#define FF 3072

typedef unsigned short u16;
typedef float f32x4 __attribute__((ext_vector_type(4)));
typedef __bf16 bf16x8 __attribute__((ext_vector_type(8)));
typedef unsigned short u16x8 __attribute__((ext_vector_type(8)));
typedef unsigned short u16x4 __attribute__((ext_vector_type(4)));

static __device__ __forceinline__ float bf2f(u16 u) {
    union { unsigned int i; float f; } c; c.i = ((unsigned int)u) << 16; return c.f;
}
// Hardware RNE convert (v_cvt_pk_bf16_f32 path)
static __device__ __forceinline__ u16 f2bf(float f) {
    return __builtin_bit_cast(u16, static_cast<__bf16>(f));
}

// ---------------------------------------------------------------------------
// bf16 MFMA GEMM core. BM=64 x BN=128 tile, BK=32, 256 threads = 4 waves
// (2x2), each wave 32x64 = 2x4 MFMA frags. Register prefetch of next K-tile.
//   A  [M,K] bf16 row-major, Bt [N,K] bf16 row-major (B transposed)
// ---------------------------------------------------------------------------
#define LDST 40
static __device__ __forceinline__ void gemm64_core(
    const u16* __restrict__ A, const u16* __restrict__ Bt,
    int N, int K,
    const float* __restrict__ bias,
    const float* __restrict__ residf, const u16* __restrict__ residb,
    float* __restrict__ C, u16* __restrict__ Cbf, int ldcbf, int cboff,
    int do_gelu, int row0, int col0, u16* As, u16* Bs)
{
    const int tid  = threadIdx.x;
    const int lane = tid & 63;
    const int w    = tid >> 6;
    const int wm = (w >> 1) * 32;
    const int wn = (w & 1) * 64;

    const int arow = tid >> 2;
    const int akc  = (tid & 3) * 8;
    const int brow = tid >> 1;
    const int bkc  = (tid & 1) * 16;

    const u16* Ap = A  + (size_t)(row0 + arow) * K + akc;
    const u16* Bp = Bt + (size_t)(col0 + brow) * K + bkc;
    u16* AsW = &As[arow * LDST + akc];
    u16* BsW = &Bs[brow * LDST + bkc];

    const int fr = lane & 15;
    const int fk = (lane >> 4) * 8;

    f32x4 acc[2][4] = {};

    u16x8 ar  = *(const u16x8*)(Ap);
    u16x8 br0 = *(const u16x8*)(Bp);
    u16x8 br1 = *(const u16x8*)(Bp + 8);

    for (int k0 = 0; k0 < K; k0 += 32) {
        if (k0) __syncthreads();
        *(u16x8*)AsW       = ar;
        *(u16x8*)BsW       = br0;
        *(u16x8*)(BsW + 8) = br1;
        __syncthreads();

        if (k0 + 32 < K) {
            ar  = *(const u16x8*)(Ap + k0 + 32);
            br0 = *(const u16x8*)(Bp + k0 + 32);
            br1 = *(const u16x8*)(Bp + k0 + 40);
        }

        bf16x8 af[2], bfv[4];
#pragma unroll
        for (int mi = 0; mi < 2; ++mi)
            af[mi] = __builtin_bit_cast(bf16x8,
                *(const u16x8*)(&As[(wm + 16 * mi + fr) * LDST + fk]));
#pragma unroll
        for (int ni = 0; ni < 4; ++ni)
            bfv[ni] = __builtin_bit_cast(bf16x8,
                *(const u16x8*)(&Bs[(wn + 16 * ni + fr) * LDST + fk]));
#pragma unroll
        for (int mi = 0; mi < 2; ++mi)
#pragma unroll
            for (int ni = 0; ni < 4; ++ni)
                acc[mi][ni] = __builtin_amdgcn_mfma_f32_16x16x32_bf16(
                    af[mi], bfv[ni], acc[mi][ni], 0, 0, 0);
    }

    const int orow0 = row0 + wm + (lane >> 4) * 4;
    const int ocol0 = col0 + wn + fr;
#pragma unroll
    for (int mi = 0; mi < 2; ++mi) {
#pragma unroll
        for (int ni = 0; ni < 4; ++ni) {
            const int col = ocol0 + ni * 16;
            const float bv = bias ? bias[col] : 0.0f;
#pragma unroll
            for (int r = 0; r < 4; ++r) {
                const int row = orow0 + mi * 16 + r;
                float v = acc[mi][ni][r] + bv;
                if (do_gelu) v = 0.5f * v * (1.0f + erff(v * 0.70710678118654752f));
                if (residf) v += residf[(size_t)row * N + col];
                if (residb) v += bf2f(residb[(size_t)row * N + col]);
                if (C)   C[(size_t)row * N + col] = v;
                if (Cbf) Cbf[(size_t)row * ldcbf + cboff + col] = f2bf(v);
            }
        }
    }
}

__global__ __launch_bounds__(256) void gemm64(
    const u16* __restrict__ A, const u16* __restrict__ Bt, int N, int K,
    const float* __restrict__ bias,
    const float* __restrict__ residf, const u16* __restrict__ residb,
    float* __restrict__ C, u16* __restrict__ Cbf, int ldcbf, int do_gelu)
{
    __shared__ u16 As[64 * LDST];
    __shared__ u16 Bs[128 * LDST];
    gemm64_core(A, Bt, N, K, bias, residf, residb, C, Cbf, ldcbf, 0, do_gelu,
                blockIdx.y * 64, blockIdx.x * 128, As, Bs);
}

__global__ __launch_bounds__(256) void gemm64_qkv3(
    const u16* __restrict__ A0, const u16* __restrict__ A1, const u16* __restrict__ A2,
    const u16* __restrict__ B0, const u16* __restrict__ B1, const u16* __restrict__ B2,
    u16* __restrict__ Cbf, int ldcbf)
{
    __shared__ u16 As[64 * LDST];
    __shared__ u16 Bs[128 * LDST];
    const int z = blockIdx.z;
    const u16* A = (z == 0) ? A0 : (z == 1) ? A1 : A2;
    const u16* B = (z == 0) ? B0 : (z == 1) ? B1 : B2;
    gemm64_core(A, B, DD, DD, nullptr, nullptr, nullptr, nullptr, Cbf, ldcbf,
                z * DD, 0, blockIdx.y * 64, blockIdx.x * 128, As, Bs);
}

// ---------------------------------------------------------------------------
// Transpose + fp32->bf16: in [K,N] fp32 (z-batched) -> out [N,K] bf16
// ---------------------------------------------------------------------------
__global__ __launch_bounds__(256) void tcvt_kernel(
    const float* __restrict__ in, u16* __restrict__ out, int K, int N)
{
    __shared__ float t[32][33];
    const float* ib = in + (size_t)blockIdx.z * K * N;
    u16* ob = out + (size_t)blockIdx.z * K * N;
    const int n0 = blockIdx.x * 32, k0 = blockIdx.y * 32;
    const int tx = threadIdx.x & 31, ty = threadIdx.x >> 5;
#pragma unroll
    for (int j = 0; j < 4; ++j)
        t[ty + j * 8][tx] = ib[(size_t)(k0 + ty + j * 8) * N + n0 + tx];
    __syncthreads();
#pragma unroll
    for (int j = 0; j < 4; ++j)
        ob[(size_t)(n0 + ty + j * 8) * K + k0 + tx] = f2bf(t[tx][ty + j * 8]);
}

// Six per-head weights [12,768,64] -> [768,768] each, stacked into Wm6.
__global__ __launch_bounds__(256) void tcvt6_kernel(
    const float* __restrict__ w0, const float* __restrict__ w1,
    const float* __restrict__ w2, const float* __restrict__ w3,
    const float* __restrict__ w4, const float* __restrict__ w5,
    u16* __restrict__ Wm6)
{
    __shared__ float t[32][33];
    const int z = blockIdx.z;
    const int wi = z / 12, head = z % 12;
    const float* wsel = (wi == 0) ? w0 : (wi == 1) ? w1 : (wi == 2) ? w2 :
                        (wi == 3) ? w3 : (wi == 4) ? w4 : w5;
    const float* ib = wsel + (size_t)head * DD * DHD;
    u16* ob = Wm6 + (size_t)wi * DD * DD + (size_t)head * DHD * DD;
    const int n0 = blockIdx.x * 32, k0 = blockIdx.y * 32;
    const int tx = threadIdx.x & 31, ty = threadIdx.x >> 5;
#pragma unroll
    for (int j = 0; j < 4; ++j)
        t[ty + j * 8][tx] = ib[(size_t)(k0 + ty + j * 8) * DHD + n0 + tx];
    __syncthreads();
#pragma unroll
    for (int j = 0; j < 4; ++j)
        ob[(size_t)(n0 + ty + j * 8) * DD + k0 + tx] = f2bf(t[tx][ty + j * 8]);
}

// fp32 -> bf16 elementwise, 3 tensors batched over z
__global__ __launch_bounds__(256) void cvt3_kernel(
    const float* __restrict__ s0, const float* __restrict__ s1,
    const float* __restrict__ s2,
    u16* __restrict__ d0, u16* __restrict__ d1, u16* __restrict__ d2, int n4)
{
    const int z = blockIdx.z;
    const float* s = (z == 0) ? s0 : (z == 1) ? s1 : s2;
    u16* d = (z == 0) ? d0 : (z == 1) ? d1 : d2;
    const int i = blockIdx.x * 256 + threadIdx.x;
    if (i < n4) {
        float4 v = ((const float4*)s)[i];
        ushort4 o;
        o.x = f2bf(v.x); o.y = f2bf(v.y); o.z = f2bf(v.z); o.w = f2bf(v.w);
        ((ushort4*)d)[i] = o;
    }
}

// ---------------------------------------------------------------------------
// MFMA flash attention. One block per (64-query tile, b*h); 4 waves, each a
// 16-query strip. bf16 in/out, fp32 softmax.
// k-dim of P/Vt stored PERMUTED by pi(j) = (j&3)*16 + (j>>2) — PV is
// invariant since both operands use the same permutation. This lets the
// softmax write P as one ds_write_b64 per row (4 bf16, j = lr*4 + fi).
// Register prefetch of next K/V tile; causal grid reversed for balance.
// ---------------------------------------------------------------------------
#define AST 72
__global__ __launch_bounds__(256) void attn_mfma_kernel(
    const u16* __restrict__ Q, const u16* __restrict__ K,
    const u16* __restrict__ V, int ldq, const int* __restrict__ kmask,
    u16* __restrict__ O, int causal)
{
    const int qt = causal ? ((int)gridDim.x - 1 - (int)blockIdx.x) : (int)blockIdx.x;
    const int bh = blockIdx.y;
    const int b  = bh / HH;
    const int h  = bh % HH;
    const int tid  = threadIdx.x;
    const int lane = tid & 63;
    const int w    = tid >> 6;
    const int lr = lane & 15;
    const int lg = lane >> 4;

    __shared__ u16 Ks[64 * AST];
    __shared__ u16 Vt[64 * AST];
    __shared__ u16 Ps[64 * AST];

    const int row0 = qt * 64;
    const int q0w  = row0 + w * 16;

    bf16x8 qf[2];
    {
        const u16* qp = Q + (size_t)(b * SS + q0w + lr) * ldq + h * DHD + lg * 8;
        qf[0] = __builtin_bit_cast(bf16x8, *(const u16x8*)(qp));
        qf[1] = __builtin_bit_cast(bf16x8, *(const u16x8*)(qp + 32));
    }

    // staging geometry
    const int sr = tid >> 2;                    // K stage row (0..63)
    const int sc = (tid & 3) * 16;              // K stage col (0,16,32,48)
    const int vkey = lane;                      // V stage key
    const int vj = ((vkey & 15) << 2) | (vkey >> 4);   // permuted column
    const int dw = w * 16;                      // V stage d-range

    f32x4 acc[4] = {};
    float m[4], l[4];
#pragma unroll
    for (int r = 0; r < 4; ++r) { m[r] = -INFINITY; l[r] = 0.0f; }

    const int nkt = causal ? (qt + 1) : 16;

    // prefetch tile 0
    u16x8 kr0, kr1, vr0, vr1;
    {
        const u16* kp = K + (size_t)(b * SS + sr) * ldq + h * DHD + sc;
        kr0 = *(const u16x8*)(kp);
        kr1 = *(const u16x8*)(kp + 8);
        const u16* vp = V + (size_t)(b * SS + vkey) * ldq + h * DHD + dw;
        vr0 = *(const u16x8*)(vp);
        vr1 = *(const u16x8*)(vp + 8);
    }

    for (int kt = 0; kt < nkt; ++kt) {
        const int kcol0 = kt * 64;
        if (kt) __syncthreads();                // prior tile's LDS reads done

        // ---- write staged regs to LDS ----
        *(u16x8*)(&Ks[sr * AST + sc])     = kr0;
        *(u16x8*)(&Ks[sr * AST + sc + 8]) = kr1;
#pragma unroll
        for (int j = 0; j < 8; ++j) Vt[(dw + j) * AST + vj] = vr0[j];
#pragma unroll
        for (int j = 0; j < 8; ++j) Vt[(dw + 8 + j) * AST + vj] = vr1[j];
        __syncthreads();

        // ---- prefetch next tile ----
        if (kt + 1 < nkt) {
            const int kn = kcol0 + 64;
            const u16* kp = K + (size_t)(b * SS + kn + sr) * ldq + h * DHD + sc;
            kr0 = *(const u16x8*)(kp);
            kr1 = *(const u16x8*)(kp + 8);
            const u16* vp = V + (size_t)(b * SS + kn + vkey) * ldq + h * DHD + dw;
            vr0 = *(const u16x8*)(vp);
            vr1 = *(const u16x8*)(vp + 8);
        }

        // ---- QK^T ----
        f32x4 s[4] = {};
#pragma unroll
        for (int fi = 0; fi < 4; ++fi) {
            bf16x8 kf0 = __builtin_bit_cast(bf16x8, *(const u16x8*)(&Ks[(fi * 16 + lr) * AST + lg * 8]));
            bf16x8 kf1 = __builtin_bit_cast(bf16x8, *(const u16x8*)(&Ks[(fi * 16 + lr) * AST + 32 + lg * 8]));
            s[fi] = __builtin_amdgcn_mfma_f32_16x16x32_bf16(qf[0], kf0, s[fi], 0, 0, 0);
            s[fi] = __builtin_amdgcn_mfma_f32_16x16x32_bf16(qf[1], kf1, s[fi], 0, 0, 0);
        }

        // ---- mask + online softmax ----
        int okv[4];
#pragma unroll
        for (int fi = 0; fi < 4; ++fi)
            okv[fi] = kmask[b * SS + kcol0 + fi * 16 + lr];
        const bool diag = (causal != 0) && (kt == qt);

#pragma unroll
        for (int r = 0; r < 4; ++r) {
            const int qrow = q0w + lg * 4 + r;
            float sv[4];
            float mx = -INFINITY;
#pragma unroll
            for (int fi = 0; fi < 4; ++fi) {
                float v = s[fi][r] * 0.125f;
                const int key = kcol0 + fi * 16 + lr;
                const bool allow = (okv[fi] != 0) && (!diag || key <= qrow);
                v = allow ? v : -INFINITY;
                sv[fi] = v;
                mx = fmaxf(mx, v);
            }
            mx = fmaxf(mx, __shfl_xor(mx, 1));
            mx = fmaxf(mx, __shfl_xor(mx, 2));
            mx = fmaxf(mx, __shfl_xor(mx, 4));
            mx = fmaxf(mx, __shfl_xor(mx, 8));

            const float nm = fmaxf(m[r], mx);
            u16x4 pk;
            if (nm > -INFINITY) {
                const float rescale = __expf(m[r] - nm);
                float rs = 0.0f;
#pragma unroll
                for (int fi = 0; fi < 4; ++fi) {
                    const float pv = __expf(sv[fi] - nm);
                    pk[fi] = f2bf(pv);
                    rs += pv;
                }
                rs += __shfl_xor(rs, 1);
                rs += __shfl_xor(rs, 2);
                rs += __shfl_xor(rs, 4);
                rs += __shfl_xor(rs, 8);
                l[r] = l[r] * rescale + rs;
                m[r] = nm;
#pragma unroll
                for (int di = 0; di < 4; ++di) acc[di][r] *= rescale;
            } else {
                pk[0] = 0; pk[1] = 0; pk[2] = 0; pk[3] = 0;
            }
            // packed P write: 4 bf16 at permuted cols j = lr*4 + fi
            *(u16x4*)(&Ps[(w * 16 + lg * 4 + r) * AST + lr * 4]) = pk;
        }

        // ---- PV (permuted k-layout on both operands) ----
#pragma unroll
        for (int kk = 0; kk < 2; ++kk) {
            bf16x8 pf = __builtin_bit_cast(bf16x8, *(const u16x8*)(&Ps[(w * 16 + lr) * AST + kk * 32 + lg * 8]));
#pragma unroll
            for (int di = 0; di < 4; ++di) {
                bf16x8 vf = __builtin_bit_cast(bf16x8, *(const u16x8*)(&Vt[(di * 16 + lr) * AST + kk * 32 + lg * 8]));
                acc[di] = __builtin_amdgcn_mfma_f32_16x16x32_bf16(pf, vf, acc[di], 0, 0, 0);
            }
        }
    }

    // ---- epilogue ----
#pragma unroll
    for (int r = 0; r < 4; ++r) {
        const float inv = (l[r] > 0.0f) ? (1.0f / l[r]) : 0.0f;
        const size_t orow = (size_t)(b * SS + q0w + lg * 4 + r) * DD + h * DHD;
#pragma unroll
        for (int di = 0; di < 4; ++di)
            O[orow + di * 16 + lr] = f2bf(acc[di][r] * inv);
    }
}

// ---------------------------------------------------------------------------
// LayerNorm over last dim (768); nullable fp32 out / bf16 out.
// ---------------------------------------------------------------------------
__global__ __launch_bounds__(256) void ln_kernel(
    const float* __restrict__ X, const float* __restrict__ gma,
    const float* __restrict__ bta, float* __restrict__ Y, u16* __restrict__ Ybf)
{
    const int row = blockIdx.x;
    const int tid = threadIdx.x;
    const float* x = X + (size_t)row * DD;

    const float v0 = x[tid], v1 = x[tid + 256], v2 = x[tid + 512];

    __shared__ float sd[256];
    sd[tid] = v0 + v1 + v2;
    __syncthreads();
    for (int off = 128; off > 0; off >>= 1) {
        if (tid < off) sd[tid] += sd[tid + off];
        __syncthreads();
    }
    const float mean = sd[0] * (1.0f / 768.0f);
    __syncthreads();

    const float q0 = v0 - mean, q1 = v1 - mean, q2 = v2 - mean;
    sd[tid] = q0 * q0 + q1 * q1 + q2 * q2;
    __syncthreads();
    for (int off = 128; off > 0; off >>= 1) {
        if (tid < off) sd[tid] += sd[tid + off];
        __syncthreads();
    }
    const float var = sd[0] * (1.0f / 768.0f);
    const float inv = rsqrtf(var + 1e-5f);

    const float y0 = q0 * inv * gma[tid]       + bta[tid];
    const float y1 = q1 * inv * gma[tid + 256] + bta[tid + 256];
    const float y2 = q2 * inv * gma[tid + 512] + bta[tid + 512];
    if (Y) {
        float* y = Y + (size_t)row * DD;
        y[tid] = y0; y[tid + 256] = y1; y[tid + 512] = y2;
    }
    if (Ybf) {
        u16* yb = Ybf + (size_t)row * DD;
        yb[tid] = f2bf(y0); yb[tid + 256] = f2bf(y1); yb[tid + 512] = f2bf(y2);
    }
}

// ---------------------------------------------------------------------------
extern "C" void kernel_launch(void* const* d_in, const int* in_sizes, int n_in,
                              void* d_out, int out_size, void* d_ws, size_t ws_size,
                              hipStream_t stream)
{
    (void)in_sizes; (void)n_in; (void)out_size; (void)ws_size;

    const float* key_enc   = (const float*)d_in[0];
    const float* value_enc = (const float*)d_in[1];
    const float* x         = (const float*)d_in[2];
    const int*   src_mask  = (const int*)d_in[3];
    const int*   tgt_mask  = (const int*)d_in[4];
    const float* Wq_m = (const float*)d_in[5];
    const float* Wk_m = (const float*)d_in[6];
    const float* Wv_m = (const float*)d_in[7];
    const float* Wo_m = (const float*)d_in[8];
    const float* Wq_c = (const float*)d_in[9];
    const float* Wk_c = (const float*)d_in[10];
    const float* Wv_c = (const float*)d_in[11];
    const float* Wo_c = (const float*)d_in[12];
    const float* ln1_g = (const float*)d_in[13];
    const float* ln1_b = (const float*)d_in[14];
    const float* ln2_g = (const float*)d_in[15];
    const float* ln2_b = (const float*)d_in[16];
    const float* ln3_g = (const float*)d_in[17];
    const float* ln3_b = (const float*)d_in[18];
    const float* W1 = (const float*)d_in[19];
    const float* b1 = (const float*)d_in[20];
    const float* W2 = (const float*)d_in[21];
    const float* b2 = (const float*)d_in[22];

    float* out = (float*)d_out;

    // ---- workspace layout (~82 MB) ----
    const size_t ACT = (size_t)MROWS * DD;
    const size_t WP  = (size_t)DD * DD;
    char* p = (char*)d_ws;
    u16* QKV  = (u16*)p;   p += 3 * ACT * 2;
    u16* BFx  = (u16*)p;   p += ACT * 2;
    u16* BFK  = (u16*)p;   p += ACT * 2;
    u16* BFV  = (u16*)p;   p += ACT * 2;
    u16* BF1a = (u16*)p;   p += ACT * 2;
    u16* BF1h = (u16*)p;   p += ACT * 2;
    float* T2 = (float*)p; p += ACT * 4;
    u16* Wm6  = (u16*)p;   p += 6 * WP * 2;
    u16* Wom_t = (u16*)p;  p += WP * 2;
    u16* Woc_t = (u16*)p;  p += WP * 2;
    u16* W1t  = (u16*)p;   p += (size_t)DD * FF * 2;
    u16* W2t  = (u16*)p;   p += (size_t)DD * FF * 2;
    u16* MID  = QKV;

    const dim3 blk(256);
    const int nc4 = (int)(ACT / 4);

    cvt3_kernel<<<dim3(nc4 / 256, 1, 3), blk, 0, stream>>>(
        x, key_enc, value_enc, BFx, BFK, BFV, nc4);
    tcvt6_kernel<<<dim3(2, 24, 72), blk, 0, stream>>>(
        Wq_m, Wk_m, Wv_m, Wq_c, Wk_c, Wv_c, Wm6);
    tcvt_kernel<<<dim3(24, 24, 1), blk, 0, stream>>>(Wo_m, Wom_t, DD, DD);
    tcvt_kernel<<<dim3(24, 24, 1), blk, 0, stream>>>(Wo_c, Woc_t, DD, DD);
    tcvt_kernel<<<dim3(96, 24, 1), blk, 0, stream>>>(W1, W1t, DD, FF);
    tcvt_kernel<<<dim3(24, 96, 1), blk, 0, stream>>>(W2, W2t, FF, DD);

    const dim3 gQKV(18, 64);
    const dim3 gP(6, 64);
    const dim3 gP3(6, 64, 3);
    const dim3 gM1(24, 64);
    const dim3 gAttn(16, BB * HH);

    // ---- Self-attention ----
    gemm64<<<gQKV, blk, 0, stream>>>(BFx, Wm6, 3 * DD, DD,
                                     nullptr, nullptr, nullptr,
                                     nullptr, QKV, 3 * DD, 0);
    attn_mfma_kernel<<<gAttn, blk, 0, stream>>>(QKV, QKV + DD, QKV + 2 * DD, 3 * DD,
                                                tgt_mask, BF1a, 1);
    gemm64<<<gP, blk, 0, stream>>>(BF1a, Wom_t, DD, DD,
                                   nullptr, x, nullptr,
                                   T2, nullptr, DD, 0);
    ln_kernel<<<MROWS, blk, 0, stream>>>(T2, ln1_g, ln1_b, nullptr, BF1h);

    // ---- Cross-attention ----
    gemm64_qkv3<<<gP3, blk, 0, stream>>>(BF1h, BFK, BFV,
                                         Wm6 + 3 * WP, Wm6 + 4 * WP, Wm6 + 5 * WP,
                                         QKV, 3 * DD);
    attn_mfma_kernel<<<gAttn, blk, 0, stream>>>(QKV, QKV + DD, QKV + 2 * DD, 3 * DD,
                                                src_mask, BF1a, 0);
    gemm64<<<gP, blk, 0, stream>>>(BF1a, Woc_t, DD, DD,
                                   nullptr, nullptr, BF1h,
                                   T2, nullptr, DD, 0);
    ln_kernel<<<MROWS, blk, 0, stream>>>(T2, ln2_g, ln2_b, nullptr, BF1h);

    // ---- MLP ----
    gemm64<<<gM1, blk, 0, stream>>>(BF1h, W1t, FF, DD,
                                    b1, nullptr, nullptr,
                                    nullptr, MID, FF, 1);
    gemm64<<<gP, blk, 0, stream>>>(MID, W2t, DD, FF,
                                   b2, nullptr, BF1h,
                                   T2, nullptr, DD, 0);
    ln_kernel<<<MROWS, blk, 0, stream>>>(T2, ln3_g, ln3_b, out, nullptr);
}